// Round 16
// baseline (348.982 us; speedup 1.0000x reference)
//
#include <hip/hip_runtime.h>
#include <hip/hip_bf16.h>
#include <math.h>

// Problem constants
#define Bq  512
#define Lq  41
#define Vq  4
#define Dq  64
#define NLq 3
#define DIq 128
#define Nq  16
#define DTRq 4
#define Kq  4
#define NSq 3
#define H1q 384
#define H2q 16
#define FLATq (Lq*Dq)   // 2624

typedef __attribute__((ext_vector_type(8))) short frag8;   // 8 bf16 (4 VGPRs)
typedef __attribute__((ext_vector_type(4))) float f32x4;

__device__ __forceinline__ float b2f(unsigned short u) {
    union { float f; unsigned int i; } v; v.i = ((unsigned int)u) << 16; return v.f;
}
__device__ __forceinline__ unsigned short f2b_rne(float f) {
    union { float f; unsigned int i; } v; v.f = f;
    unsigned int x = v.i;
    return (unsigned short)((x + 0x7fffu + ((x >> 16) & 1u)) >> 16);
}
__device__ __forceinline__ unsigned short f2b_tr(float f) {
    union { float f; unsigned int i; } v; v.f = f;
    return (unsigned short)(v.i >> 16);
}
__device__ __forceinline__ float fast_rcp(float x) { return __builtin_amdgcn_rcpf(x); }

// ---------------------------------------------------------------------------
// prep: blocks [0,246) transpose W1 -> W1b bf16 [384][2624];
//       blocks [246,1326) convert/transpose small weights;
//       block 1326 checks A-delta uniformity per (s,layer) -> Aflag[9]
//       (enables geometric-chain dA in the scan; falls back if not uniform).
// ---------------------------------------------------------------------------
__global__ __launch_bounds__(256) void prep_kernel(const float* __restrict__ W1,
                                                   const float* __restrict__ in_proj,
                                                   const float* __restrict__ x_proj,
                                                   const float* __restrict__ out_proj,
                                                   const float* __restrict__ A_log,
                                                   unsigned short* __restrict__ W1b,
                                                   unsigned short* __restrict__ Wb_in,
                                                   unsigned short* __restrict__ xp_b,
                                                   unsigned short* __restrict__ op_b,
                                                   int* __restrict__ Aflag) {
    const int bx = blockIdx.x;
    if (bx < 246) {
        __shared__ float t[64][65];
        const int k0 = (bx / 6) * 64, n0 = (bx % 6) * 64;
        for (int idx = threadIdx.x; idx < 4096; idx += 256) {
            int kr = idx >> 6, nc = idx & 63;
            t[kr][nc] = W1[(size_t)(k0 + kr) * H1q + n0 + nc];
        }
        __syncthreads();
        for (int idx = threadIdx.x; idx < 4096; idx += 256) {
            int nr = idx >> 6, kc = idx & 63;
            W1b[(size_t)(n0 + nr) * FLATq + k0 + kc] = f2b_rne(t[kc][nr]);
        }
        return;
    }
    if (bx == 246 + 1080) {
        // A-structure uniformity flags: for each sl, check that within every
        // (d, half) 8-state group, A[n+1]-A[n] is constant (A = -exp(A_log)).
        const int tid = threadIdx.x;
        const int d = tid >> 1, half = tid & 1;
        for (int sl = 0; sl < 9; ++sl) {
            const float* al = A_log + (size_t)sl * (DIq * Nq) + d * Nq + half * 8;
            float A2[8];
            #pragma unroll
            for (int n = 0; n < 8; ++n) A2[n] = -__expf(al[n]);
            float d0 = A2[1] - A2[0];
            int ok = 1;
            #pragma unroll
            for (int n = 2; n < 8; ++n) {
                float dk = A2[n] - A2[n-1];
                if (!(fabsf(dk - d0) <= 1e-4f * fabsf(d0) + 1e-12f)) ok = 0;
            }
            int allok = __syncthreads_and(ok);
            if (tid == 0) Aflag[sl] = allok;
        }
        return;
    }
    int idx = (bx - 246) * 256 + threadIdx.x;
    if (idx < 9*256*64) {
        int sl = idx >> 14, rem = idx & 16383;
        int n = rem >> 6, k = rem & 63;
        Wb_in[idx] = f2b_rne(in_proj[(size_t)sl*16384 + k*256 + n]);
    } else if (idx < 9*256*64 + 9*48*128) {
        int i2 = idx - 9*256*64;
        int sl = i2 / 6144, rem = i2 % 6144;
        int c = rem >> 7, k = rem & 127;
        float v = (c < 36) ? x_proj[(size_t)sl*(128*36) + k*36 + c] : 0.f;
        xp_b[i2] = f2b_rne(v);
    } else if (idx < 9*256*64 + 9*48*128 + 9*64*128) {
        int i3 = idx - (9*256*64 + 9*48*128);
        int sl = i3 >> 13, rem = i3 & 8191;
        int n = rem >> 7, k = rem & 127;
        op_b[i3] = f2b_rne(out_proj[(size_t)sl*8192 + k*64 + n]);
    }
}

// ---------------------------------------------------------------------------
// mamba_stack: ALL 3 layers for one (s,b), residual kept in LDS.
// ROUND-15: manual software-pipelining (register rotation) of the scan and
// conv. Evidence: fence-removal was a codegen no-op (r10) and occupancy is
// irrelevant (r8-13 ≈55% VALUBusy at 3/4/6 waves/SIMD) — each scan step ends
// with an LDS store (u_lb[l] = z) that the compiler cannot move the next
// step's LDS loads above (may-alias). Rotation issues step l+1's loads
// (u, B0/B1/C0/C1, rs, next softplus q0) BEFORE step l's store — legal since
// row l+1 is written only at step l+1. Conv gets the same cur-prefetch.
// LDS: xt 12464 (stride 76) + u 11152 + rs 10824 + union{xn|dbl} 6560 = 41000 B
// ---------------------------------------------------------------------------
__global__ __launch_bounds__(256, 2) void mamba_stack(
    unsigned short* __restrict__ Xn,            // [NS][B][FLAT] bf16 OUTPUT
    const int* __restrict__ ids,
    const float* __restrict__ emb,
    const unsigned short* __restrict__ Wb_in,   // [9][256][64]
    const float* __restrict__ conv_w,
    const float* __restrict__ conv_b,
    const unsigned short* __restrict__ xp_b,    // [9][48][128]
    const float* __restrict__ dt_w,
    const float* __restrict__ dt_b,
    const float* __restrict__ A_log,
    const float* __restrict__ Dp,
    const unsigned short* __restrict__ op_b,    // [9][64][128]
    const float* __restrict__ norm_w,
    const float* __restrict__ norm_f_w,
    const float* __restrict__ fusion_w,
    const int* __restrict__ Aflag)              // [9] uniform-A flags
{
    const int b = blockIdx.x, s = blockIdx.y, tid = threadIdx.x;
    const int wave = tid >> 6, lane = tid & 63;
    const int nl = lane & 15, quad = lane >> 4;

    __shared__ float          xt  [Lq][76];     // residual stream (fp32), stride 76
    __shared__ unsigned short u_lb[Lq][136];    // bf16 u; z in place after scan
    __shared__ unsigned short rs_lb[Lq][132];   // bf16 silu(res)
    __shared__ __align__(16) char un_buf[6560]; // union: xn (A->B) | dbl (D->F)
    unsigned short (*xn_lb)[72] = (unsigned short(*)[72])un_buf;
    float          (*dbl_s)[40] = (float(*)[40])un_buf;

    // ---- residual init from embedding (layer 0) --------------------------
    for (int l = wave; l < Lq; l += 4) {
        int id = ids[b * Lq + l];
        xt[l][lane] = emb[id * Dq + lane];
    }

    for (int layer = 0; layer < NLq; ++layer) {
        const int sl = s * NLq + layer;

        // ---- A: rmsnorm(xt) -> xn bf16 -----------------------------------
        {
            const float nwv = norm_w[(size_t)sl * Dq + lane];
            for (int l = wave; l < Lq; l += 4) {
                float v  = xt[l][lane];
                float ss = v * v;
                #pragma unroll
                for (int off = 32; off; off >>= 1) ss += __shfl_xor(ss, off, 64);
                float scale = __builtin_amdgcn_rsqf(ss * (1.0f / Dq) + 1e-5f);
                xn_lb[l][lane] = f2b_tr(v * scale * nwv);
            }
        }
        __syncthreads();

        // ---- B: [48,64]@[64,256] MFMA -> u (cols<128), silu -> rs --------
        {
            #pragma unroll
            for (int t = 0; t < 12; ++t) {
                const int id = wave * 12 + t;
                const int mt = id >> 4, nt = id & 15;
                int ar = mt * 16 + nl; if (ar > Lq - 1) ar = Lq - 1;   // rows>40: clamp, output discarded
                const unsigned short* Wp = Wb_in + ((size_t)(sl * 256 + nt * 16 + nl)) * 64 + quad * 8;
                frag8 a0 = *(const frag8*)&xn_lb[ar][quad * 8];
                frag8 a1 = *(const frag8*)&xn_lb[ar][32 + quad * 8];
                frag8 b0 = *(const frag8*)&Wp[0];
                frag8 b1 = *(const frag8*)&Wp[32];
                f32x4 c = {0.f, 0.f, 0.f, 0.f};
                c = __builtin_amdgcn_mfma_f32_16x16x32_bf16(a0, b0, c, 0, 0, 0);
                c = __builtin_amdgcn_mfma_f32_16x16x32_bf16(a1, b1, c, 0, 0, 0);
                const int col = nt * 16 + nl;
                const int r0 = mt * 16 + quad * 4;
                if (col < DIq) {
                    #pragma unroll
                    for (int r = 0; r < 4; ++r) {
                        int row = r0 + r;
                        if (row < Lq) u_lb[row][col] = f2b_tr(c[r]);
                    }
                } else {
                    const int d = col - DIq;
                    #pragma unroll
                    for (int r = 0; r < 4; ++r) {
                        int row = r0 + r;
                        if (row < Lq) {
                            float v = c[r];
                            rs_lb[row][d] = f2b_tr(v * fast_rcp(1.f + __expf(-v)));
                        }
                    }
                }
            }
        }
        __syncthreads();

        // ---- C: depthwise causal conv (K=4) + bias + silu, in place ------
        // cur prefetched one step ahead (issued before the in-place store so
        // the load isn't serialized behind the may-aliasing write).
        {
            const float* cw = conv_w + (size_t)sl * (DIq * Kq);
            const int d = tid >> 1, half = tid & 1;
            const float c0 = cw[d*4+0], c1 = cw[d*4+1], c2 = cw[d*4+2], c3 = cw[d*4+3];
            const float cbv = conv_b[(size_t)sl * DIq + d];
            float w0 = 0.f, w1 = 0.f, w2 = 0.f;
            if (half) { w0 = b2f(u_lb[18][d]); w1 = b2f(u_lb[19][d]); w2 = b2f(u_lb[20][d]); }
            const int base = half ? 21 : 0;
            const int cnt  = half ? 20 : 21;
            float cur_n = b2f(u_lb[base][d]);
            for (int i = 0; i < cnt; ++i) {
                int l = base + i;
                float cur = cur_n;
                if (i + 1 < cnt) cur_n = b2f(u_lb[l + 1][d]);
                float a = fmaf(w0, c0, fmaf(w1, c1, fmaf(w2, c2, fmaf(cur, c3, cbv))));
                u_lb[l][d] = f2b_tr(a * fast_rcp(1.f + __expf(-a)));
                w0 = w1; w1 = w2; w2 = cur;
            }
        }
        __syncthreads();

        // ---- D: dbl = u[48,128] @ xp[128,48] MFMA (keep cols<40) ---------
        {
            for (int t = wave; t < 9; t += 4) {
                const int mt = t / 3, ct = t % 3;
                int ar = mt * 16 + nl; if (ar > Lq - 1) ar = Lq - 1;
                f32x4 c = {0.f, 0.f, 0.f, 0.f};
                #pragma unroll
                for (int kt = 0; kt < 4; ++kt) {
                    frag8 a  = *(const frag8*)&u_lb[ar][kt * 32 + quad * 8];
                    frag8 bb = *(const frag8*)&xp_b[((size_t)(sl * 48 + ct * 16 + nl)) * 128 + kt * 32 + quad * 8];
                    c = __builtin_amdgcn_mfma_f32_16x16x32_bf16(a, bb, c, 0, 0, 0);
                }
                const int col = ct * 16 + nl, r0 = mt * 16 + quad * 4;
                if (col < 40) {
                    #pragma unroll
                    for (int r = 0; r < 4; ++r) {
                        int row = r0 + r;
                        if (row < Lq) dbl_s[row][col] = c[r];
                    }
                }
            }
        }
        __syncthreads();

        // ---- F: selective scan, fp32 state; z -> u_lb in place -----------
        // Register-rotated: step l+1's LDS loads are issued before step l's
        // u_lb store (compiler can't do this itself — may-alias). Paired
        // softplus via shfl_xor; geometric dA chain when Aflag[sl].
        {
            const int d = tid >> 1, half = tid & 1;
            const float* al = A_log + (size_t)sl * (DIq * Nq) + d * Nq + half * 8;
            float A2[8], h[8];
            #pragma unroll
            for (int n = 0; n < 8; ++n) {
                A2[n] = -__expf(al[n]) * 1.442695041f;   // fold log2(e) into A
                h[n] = 0.f;
            }
            const float dd = A2[1] - A2[0];
            const bool fastA = __builtin_amdgcn_readfirstlane(Aflag[sl]) != 0;
            const float* dw = dt_w + (size_t)sl * (DTRq * DIq);
            const float dw0 = dw[d], dw1 = dw[DIq + d], dw2 = dw[2*DIq + d], dw3 = dw[3*DIq + d];
            const float dbv = dt_b[(size_t)sl * DIq + d];
            const float dpd = Dp[(size_t)sl * DIq + d];

            // prologue: loads for l = 0 and the first softplus inputs
            float4 q0c = *(const float4*)&dbl_s[half][0];   // lme = 0 + half (<= 40)
            float  u_n  = b2f(u_lb[0][d]);
            float4 B0n = *(const float4*)&dbl_s[0][4  + half * 8];
            float4 B1n = *(const float4*)&dbl_s[0][8  + half * 8];
            float4 C0n = *(const float4*)&dbl_s[0][20 + half * 8];
            float4 C1n = *(const float4*)&dbl_s[0][24 + half * 8];
            float  rs_n = 0.f; if (!half) rs_n = b2f(rs_lb[0][d]);
            float dts = 0.f, dto = 0.f;

            #pragma unroll 2
            for (int l = 0; l < Lq; ++l) {
                // rotate current state
                float  u_c  = u_n;
                float4 B0c = B0n, B1c = B1n, C0c = C0n, C1c = C1n;
                float  rs_c = rs_n;
                // issue next step's loads BEFORE this step's store
                if (l + 1 < Lq) {
                    u_n  = b2f(u_lb[l + 1][d]);
                    B0n = *(const float4*)&dbl_s[l + 1][4  + half * 8];
                    B1n = *(const float4*)&dbl_s[l + 1][8  + half * 8];
                    C0n = *(const float4*)&dbl_s[l + 1][20 + half * 8];
                    C1n = *(const float4*)&dbl_s[l + 1][24 + half * 8];
                    if (!half) rs_n = b2f(rs_lb[l + 1][d]);
                }
                if ((l & 1) == 0) {
                    // softplus for this pair (half computes l, partner l+1)
                    float x = fmaf(q0c.x, dw0, fmaf(q0c.y, dw1, fmaf(q0c.z, dw2, fmaf(q0c.w, dw3, dbv))));
                    dts = fmaxf(x, 0.f) + __logf(1.f + __expf(-fabsf(x)));
                    dto = __shfl_xor(dts, 1, 64);
                    if (l + 2 < Lq) {
                        int lme = l + 2 + half; if (lme > Lq - 1) lme = Lq - 1;
                        q0c = *(const float4*)&dbl_s[lme][0];
                    }
                }
                float dt_ = ((l & 1) == 0) ? (half ? dto : dts) : (half ? dts : dto);

                float dtu = dt_ * u_c;
                float a0, a1, a2, a3, a4, a5, a6, a7;
                if (fastA) {
                    a0 = __builtin_amdgcn_exp2f(dt_ * A2[0]);
                    float r = __builtin_amdgcn_exp2f(dt_ * dd);
                    a1 = a0 * r; a2 = a1 * r; a3 = a2 * r; a4 = a3 * r;
                    a5 = a4 * r; a6 = a5 * r; a7 = a6 * r;
                } else {
                    a0 = __builtin_amdgcn_exp2f(dt_ * A2[0]);
                    a1 = __builtin_amdgcn_exp2f(dt_ * A2[1]);
                    a2 = __builtin_amdgcn_exp2f(dt_ * A2[2]);
                    a3 = __builtin_amdgcn_exp2f(dt_ * A2[3]);
                    a4 = __builtin_amdgcn_exp2f(dt_ * A2[4]);
                    a5 = __builtin_amdgcn_exp2f(dt_ * A2[5]);
                    a6 = __builtin_amdgcn_exp2f(dt_ * A2[6]);
                    a7 = __builtin_amdgcn_exp2f(dt_ * A2[7]);
                }
                float y = 0.f;
                h[0] = fmaf(a0, h[0], B0c.x * dtu); y = fmaf(h[0], C0c.x, y);
                h[1] = fmaf(a1, h[1], B0c.y * dtu); y = fmaf(h[1], C0c.y, y);
                h[2] = fmaf(a2, h[2], B0c.z * dtu); y = fmaf(h[2], C0c.z, y);
                h[3] = fmaf(a3, h[3], B0c.w * dtu); y = fmaf(h[3], C0c.w, y);
                h[4] = fmaf(a4, h[4], B1c.x * dtu); y = fmaf(h[4], C1c.x, y);
                h[5] = fmaf(a5, h[5], B1c.y * dtu); y = fmaf(h[5], C1c.y, y);
                h[6] = fmaf(a6, h[6], B1c.z * dtu); y = fmaf(h[6], C1c.z, y);
                h[7] = fmaf(a7, h[7], B1c.w * dtu); y = fmaf(h[7], C1c.w, y);
                y += __shfl_xor(y, 1, 64);
                if (!half) {
                    u_lb[l][d] = f2b_tr(fmaf(u_c, dpd, y) * rs_c);
                }
            }
        }
        __syncthreads();

        // ---- G: xt += z[48,128] @ op[128,64] MFMA (LDS accumulate) -------
        {
            const int ntG = wave;
            for (int mt = 0; mt < 3; ++mt) {
                int ar = mt * 16 + nl; if (ar > Lq - 1) ar = Lq - 1;
                f32x4 c = {0.f, 0.f, 0.f, 0.f};
                #pragma unroll
                for (int kt = 0; kt < 4; ++kt) {
                    frag8 a  = *(const frag8*)&u_lb[ar][kt * 32 + quad * 8];
                    frag8 bb = *(const frag8*)&op_b[((size_t)(sl * 64 + ntG * 16 + nl)) * 128 + kt * 32 + quad * 8];
                    c = __builtin_amdgcn_mfma_f32_16x16x32_bf16(a, bb, c, 0, 0, 0);
                }
                const int j = ntG * 16 + nl, r0 = mt * 16 + quad * 4;
                #pragma unroll
                for (int r = 0; r < 4; ++r) {
                    int row = r0 + r;
                    if (row < Lq) xt[row][j] += c[r];
                }
            }
        }
        __syncthreads();
    }

    // ---- Epilogue: fused final rmsnorm + fusion weighting -> Xn bf16 -----
    {
        float fw0 = fusion_w[0], fw1 = fusion_w[1], fw2 = fusion_w[2];
        float mx = fmaxf(fw0, fmaxf(fw1, fw2));
        float e0 = __expf(fw0 - mx), e1 = __expf(fw1 - mx), e2 = __expf(fw2 - mx);
        float sw = (s == 0 ? e0 : (s == 1 ? e1 : e2)) * fast_rcp(e0 + e1 + e2);
        float nf = norm_f_w[lane] * sw;
        unsigned short* xr = Xn + ((size_t)s * Bq + b) * FLATq;
        for (int l = wave; l < Lq; l += 4) {
            float v  = xt[l][lane];
            float ss = v * v;
            #pragma unroll
            for (int off = 32; off; off >>= 1) ss += __shfl_xor(ss, off, 64);
            float scale = __builtin_amdgcn_rsqf(ss * (1.0f / Dq) + 1e-5f);
            xr[l * Dq + lane] = f2b_tr(v * scale * nf);
        }
    }
}

// ---------------------------------------------------------------------------
// head_gemm1: H1 = relu( (Σ_s Xn_s) @ W1 + b1 ). 192 blocks on 256 CUs ->
// single-block latency matters: 3 independent accumulators (c0/c1/c2, summed
// at the end) give 3x MFMA ILP (round-14: confirmed ~4 µs total win).
// ---------------------------------------------------------------------------
__global__ __launch_bounds__(256) void head_gemm1(const unsigned short* __restrict__ Xn,
                                                  const unsigned short* __restrict__ W1b,
                                                  const float* __restrict__ b1,
                                                  float* __restrict__ H1) {
    const int tid = threadIdx.x;
    const int wave = tid >> 6, lane = tid & 63;
    const int nl = lane & 15, quad = lane >> 4;
    const int mt = blockIdx.x, nt = blockIdx.y;

    __shared__ float red[4][16][17];

    const int kbeg = (wave < 2) ? wave * 21 : 42 + (wave - 2) * 20;
    const int kcnt = (wave < 2) ? 21 : 20;
    const size_t SB = (size_t)Bq * FLATq;
    const unsigned short* A0 = Xn  + (size_t)(mt * 16 + nl) * FLATq + quad * 8;
    const unsigned short* Br = W1b + (size_t)(nt * 16 + nl) * FLATq + quad * 8;

    f32x4 c0 = {0.f, 0.f, 0.f, 0.f};
    f32x4 c1 = {0.f, 0.f, 0.f, 0.f};
    f32x4 c2 = {0.f, 0.f, 0.f, 0.f};
    for (int ks = kbeg; ks < kbeg + kcnt; ++ks) {
        const int off = ks * 32;
        frag8 bb = *(const frag8*)(Br + off);
        frag8 a0 = *(const frag8*)(A0 + off);
        frag8 a1 = *(const frag8*)(A0 + SB + off);
        frag8 a2 = *(const frag8*)(A0 + 2 * SB + off);
        c0 = __builtin_amdgcn_mfma_f32_16x16x32_bf16(a0, bb, c0, 0, 0, 0);
        c1 = __builtin_amdgcn_mfma_f32_16x16x32_bf16(a1, bb, c1, 0, 0, 0);
        c2 = __builtin_amdgcn_mfma_f32_16x16x32_bf16(a2, bb, c2, 0, 0, 0);
    }
    #pragma unroll
    for (int r = 0; r < 4; ++r) red[wave][quad * 4 + r][nl] = c0[r] + c1[r] + c2[r];
    __syncthreads();

    const int row = tid >> 4, colv = tid & 15;
    float acc = red[0][row][colv] + red[1][row][colv]
              + red[2][row][colv] + red[3][row][colv];
    const int col = nt * 16 + colv;
    H1[(size_t)(mt * 16 + row) * H1q + col] = fmaxf(acc + b1[col], 0.f);
}

// ---------------------------------------------------------------------------
// head_final: h2 = relu(H1@W2+b2); out = sigmoid(h2@W3+b3). 16 batches/block.
// ---------------------------------------------------------------------------
__global__ __launch_bounds__(256) void head_final(const float* __restrict__ H1,
                                                  const float* __restrict__ W2,
                                                  const float* __restrict__ b2,
                                                  const float* __restrict__ W3,
                                                  const float* __restrict__ b3,
                                                  float* __restrict__ out) {
    const int b0 = blockIdx.x * 16, tid = threadIdx.x;
    __shared__ float H1s[16 * H1q];
    __shared__ float h2s[16][16];
    for (int idx = tid; idx < 16 * H1q; idx += 256)
        H1s[idx] = H1[(size_t)b0 * H1q + idx];
    __syncthreads();
    {
        const int row = tid >> 4, g = tid & 15;
        float acc = b2[g];
        for (int k = 0; k < H1q; ++k)
            acc = fmaf(H1s[row * H1q + k], W2[k * H2q + g], acc);
        h2s[row][g] = fmaxf(acc, 0.f);
    }
    __syncthreads();
    if (tid < 16) {
        float z = b3[0];
        #pragma unroll
        for (int k = 0; k < H2q; ++k) z = fmaf(h2s[tid][k], W3[k], z);
        out[b0 + tid] = fast_rcp(1.f + __expf(-z));
    }
}

// ---------------------------------------------------------------------------
extern "C" void kernel_launch(void* const* d_in, const int* in_sizes, int n_in,
                              void* d_out, int out_size, void* d_ws, size_t ws_size,
                              hipStream_t stream) {
    const int*   ids      = (const int*)  d_in[0];
    const float* emb      = (const float*)d_in[1];
    const float* in_proj  = (const float*)d_in[2];
    const float* conv_w   = (const float*)d_in[3];
    const float* conv_b   = (const float*)d_in[4];
    const float* x_proj   = (const float*)d_in[5];
    const float* dt_w     = (const float*)d_in[6];
    const float* dt_b     = (const float*)d_in[7];
    const float* A_log    = (const float*)d_in[8];
    const float* Dp       = (const float*)d_in[9];
    const float* out_proj = (const float*)d_in[10];
    const float* norm_w   = (const float*)d_in[11];
    const float* norm_f_w = (const float*)d_in[12];
    const float* fusion_w = (const float*)d_in[13];
    const float* W1       = (const float*)d_in[14];
    const float* b1       = (const float*)d_in[15];
    const float* W2       = (const float*)d_in[16];
    const float* b2       = (const float*)d_in[17];
    const float* W3       = (const float*)d_in[18];
    const float* b3       = (const float*)d_in[19];
    float* out = (float*)d_out;

    // workspace (shorts unless noted):
    //   Xn    3*512*2624 = 4,030,464
    //   Wb_in   147,456 | xp_b 55,296 | op_b 73,728 | W1b 1,007,616
    //   H1 (fp32) 512*384 = 196,608 floats
    //   Aflag: aliased onto the first 9 ints of H1 (prep writes, mamba_stack
    //   reads, head_gemm1 overwrites H1 only after mamba_stack completes).
    unsigned short* Xn    = (unsigned short*)d_ws;
    unsigned short* Wb_in = Xn    + (size_t)NSq * Bq * FLATq;
    unsigned short* xp_b  = Wb_in + 9*256*64;
    unsigned short* op_b  = xp_b  + 9*48*128;
    unsigned short* W1b   = op_b  + 9*64*128;
    float*          H1    = (float*)(W1b + (size_t)H1q * FLATq);
    int*            Aflag = (int*)H1;

    hipLaunchKernelGGL(prep_kernel, dim3(246 + 1080 + 1), dim3(256), 0, stream,
                       W1, in_proj, x_proj, out_proj, A_log, W1b, Wb_in, xp_b, op_b, Aflag);

    hipLaunchKernelGGL(mamba_stack, dim3(Bq, NSq), dim3(256), 0, stream,
                       Xn, ids, emb, Wb_in, conv_w, conv_b, xp_b, dt_w, dt_b,
                       A_log, Dp, op_b, norm_w, norm_f_w, fusion_w, Aflag);

    hipLaunchKernelGGL(head_gemm1, dim3(Bq/16, H1q/64), dim3(256), 0, stream,
                       Xn, W1b, b1, H1);

    hipLaunchKernelGGL(head_final, dim3(Bq/16), dim3(256), 0, stream,
                       H1, W2, b2, W3, b3, out);
}

// Round 18
// 295.176 us; speedup vs baseline: 1.1823x; 1.1823x over previous
//
#include <hip/hip_runtime.h>
#include <hip/hip_bf16.h>
#include <math.h>

// Problem constants
#define Bq  512
#define Lq  41
#define Vq  4
#define Dq  64
#define NLq 3
#define DIq 128
#define Nq  16
#define DTRq 4
#define Kq  4
#define NSq 3
#define H1q 384
#define H2q 16
#define FLATq (Lq*Dq)   // 2624

typedef __attribute__((ext_vector_type(8))) short frag8;   // 8 bf16 (4 VGPRs)
typedef __attribute__((ext_vector_type(4))) float f32x4;

__device__ __forceinline__ float b2f(unsigned short u) {
    union { float f; unsigned int i; } v; v.i = ((unsigned int)u) << 16; return v.f;
}
__device__ __forceinline__ unsigned short f2b_rne(float f) {
    union { float f; unsigned int i; } v; v.f = f;
    unsigned int x = v.i;
    return (unsigned short)((x + 0x7fffu + ((x >> 16) & 1u)) >> 16);
}
__device__ __forceinline__ unsigned short f2b_tr(float f) {
    union { float f; unsigned int i; } v; v.f = f;
    return (unsigned short)(v.i >> 16);
}
__device__ __forceinline__ float fast_rcp(float x) { return __builtin_amdgcn_rcpf(x); }

// ---------------------------------------------------------------------------
// prep: blocks [0,246) transpose W1 -> W1b bf16 [384][2624];
//       blocks [246,1326) convert/transpose small weights;
//       block 1326 checks A-delta uniformity per (s,layer) -> Aflag[9]
//       (enables geometric-chain dA in the scan; falls back if not uniform).
// ---------------------------------------------------------------------------
__global__ __launch_bounds__(256) void prep_kernel(const float* __restrict__ W1,
                                                   const float* __restrict__ in_proj,
                                                   const float* __restrict__ x_proj,
                                                   const float* __restrict__ out_proj,
                                                   const float* __restrict__ A_log,
                                                   unsigned short* __restrict__ W1b,
                                                   unsigned short* __restrict__ Wb_in,
                                                   unsigned short* __restrict__ xp_b,
                                                   unsigned short* __restrict__ op_b,
                                                   int* __restrict__ Aflag) {
    const int bx = blockIdx.x;
    if (bx < 246) {
        __shared__ float t[64][65];
        const int k0 = (bx / 6) * 64, n0 = (bx % 6) * 64;
        for (int idx = threadIdx.x; idx < 4096; idx += 256) {
            int kr = idx >> 6, nc = idx & 63;
            t[kr][nc] = W1[(size_t)(k0 + kr) * H1q + n0 + nc];
        }
        __syncthreads();
        for (int idx = threadIdx.x; idx < 4096; idx += 256) {
            int nr = idx >> 6, kc = idx & 63;
            W1b[(size_t)(n0 + nr) * FLATq + k0 + kc] = f2b_rne(t[kc][nr]);
        }
        return;
    }
    if (bx == 246 + 1080) {
        // A-structure uniformity flags: for each sl, check that within every
        // (d, half) 8-state group, A[n+1]-A[n] is constant (A = -exp(A_log)).
        const int tid = threadIdx.x;
        const int d = tid >> 1, half = tid & 1;
        for (int sl = 0; sl < 9; ++sl) {
            const float* al = A_log + (size_t)sl * (DIq * Nq) + d * Nq + half * 8;
            float A2[8];
            #pragma unroll
            for (int n = 0; n < 8; ++n) A2[n] = -__expf(al[n]);
            float d0 = A2[1] - A2[0];
            int ok = 1;
            #pragma unroll
            for (int n = 2; n < 8; ++n) {
                float dk = A2[n] - A2[n-1];
                if (!(fabsf(dk - d0) <= 1e-4f * fabsf(d0) + 1e-12f)) ok = 0;
            }
            int allok = __syncthreads_and(ok);
            if (tid == 0) Aflag[sl] = allok;
        }
        return;
    }
    int idx = (bx - 246) * 256 + threadIdx.x;
    if (idx < 9*256*64) {
        int sl = idx >> 14, rem = idx & 16383;
        int n = rem >> 6, k = rem & 63;
        Wb_in[idx] = f2b_rne(in_proj[(size_t)sl*16384 + k*256 + n]);
    } else if (idx < 9*256*64 + 9*48*128) {
        int i2 = idx - 9*256*64;
        int sl = i2 / 6144, rem = i2 % 6144;
        int c = rem >> 7, k = rem & 127;
        float v = (c < 36) ? x_proj[(size_t)sl*(128*36) + k*36 + c] : 0.f;
        xp_b[i2] = f2b_rne(v);
    } else if (idx < 9*256*64 + 9*48*128 + 9*64*128) {
        int i3 = idx - (9*256*64 + 9*48*128);
        int sl = i3 >> 13, rem = i3 & 8191;
        int n = rem >> 7, k = rem & 127;
        op_b[i3] = f2b_rne(out_proj[(size_t)sl*8192 + k*64 + n]);
    }
}

// ---------------------------------------------------------------------------
// mamba_stack: ALL 3 layers for one (s,b), residual kept in LDS.
// BEST-MEASURED configuration (round 9/10/14: mamba ~186-196 µs):
// 256 threads, __launch_bounds__(256,2) (relaxed VGPR budget — (256,4) pinned
// 64 VGPR and spilled 24 f32/thread), xt stride 76 (bank-conflict fix +
// 3 blk/CU), scalar dA chain, paired softplus, no sched fences.
// Falsified alternatives (measured): 8-wave blocks (r13: +20%), register
// rotation (r16: +25%), fences (r10: null), residency shaping (r9: null).
// LDS: xt 12464 (stride 76) + u 11152 + rs 10824 + union{xn|dbl} 6560 = 41000 B
// ---------------------------------------------------------------------------
__global__ __launch_bounds__(256, 2) void mamba_stack(
    unsigned short* __restrict__ Xn,            // [NS][B][FLAT] bf16 OUTPUT
    const int* __restrict__ ids,
    const float* __restrict__ emb,
    const unsigned short* __restrict__ Wb_in,   // [9][256][64]
    const float* __restrict__ conv_w,
    const float* __restrict__ conv_b,
    const unsigned short* __restrict__ xp_b,    // [9][48][128]
    const float* __restrict__ dt_w,
    const float* __restrict__ dt_b,
    const float* __restrict__ A_log,
    const float* __restrict__ Dp,
    const unsigned short* __restrict__ op_b,    // [9][64][128]
    const float* __restrict__ norm_w,
    const float* __restrict__ norm_f_w,
    const float* __restrict__ fusion_w,
    const int* __restrict__ Aflag)              // [9] uniform-A flags
{
    const int b = blockIdx.x, s = blockIdx.y, tid = threadIdx.x;
    const int wave = tid >> 6, lane = tid & 63;
    const int nl = lane & 15, quad = lane >> 4;

    __shared__ float          xt  [Lq][76];     // residual stream (fp32), stride 76
    __shared__ unsigned short u_lb[Lq][136];    // bf16 u; z in place after scan
    __shared__ unsigned short rs_lb[Lq][132];   // bf16 silu(res)
    __shared__ __align__(16) char un_buf[6560]; // union: xn (A->B) | dbl (D->F)
    unsigned short (*xn_lb)[72] = (unsigned short(*)[72])un_buf;
    float          (*dbl_s)[40] = (float(*)[40])un_buf;

    // ---- residual init from embedding (layer 0) --------------------------
    for (int l = wave; l < Lq; l += 4) {
        int id = ids[b * Lq + l];
        xt[l][lane] = emb[id * Dq + lane];
    }

    for (int layer = 0; layer < NLq; ++layer) {
        const int sl = s * NLq + layer;

        // ---- A: rmsnorm(xt) -> xn bf16 -----------------------------------
        {
            const float nwv = norm_w[(size_t)sl * Dq + lane];
            for (int l = wave; l < Lq; l += 4) {
                float v  = xt[l][lane];
                float ss = v * v;
                #pragma unroll
                for (int off = 32; off; off >>= 1) ss += __shfl_xor(ss, off, 64);
                float scale = __builtin_amdgcn_rsqf(ss * (1.0f / Dq) + 1e-5f);
                xn_lb[l][lane] = f2b_tr(v * scale * nwv);
            }
        }
        __syncthreads();

        // ---- B: [48,64]@[64,256] MFMA -> u (cols<128), silu -> rs --------
        {
            #pragma unroll
            for (int t = 0; t < 12; ++t) {
                const int id = wave * 12 + t;
                const int mt = id >> 4, nt = id & 15;
                int ar = mt * 16 + nl; if (ar > Lq - 1) ar = Lq - 1;   // rows>40: clamp, output discarded
                const unsigned short* Wp = Wb_in + ((size_t)(sl * 256 + nt * 16 + nl)) * 64 + quad * 8;
                frag8 a0 = *(const frag8*)&xn_lb[ar][quad * 8];
                frag8 a1 = *(const frag8*)&xn_lb[ar][32 + quad * 8];
                frag8 b0 = *(const frag8*)&Wp[0];
                frag8 b1 = *(const frag8*)&Wp[32];
                f32x4 c = {0.f, 0.f, 0.f, 0.f};
                c = __builtin_amdgcn_mfma_f32_16x16x32_bf16(a0, b0, c, 0, 0, 0);
                c = __builtin_amdgcn_mfma_f32_16x16x32_bf16(a1, b1, c, 0, 0, 0);
                const int col = nt * 16 + nl;
                const int r0 = mt * 16 + quad * 4;
                if (col < DIq) {
                    #pragma unroll
                    for (int r = 0; r < 4; ++r) {
                        int row = r0 + r;
                        if (row < Lq) u_lb[row][col] = f2b_tr(c[r]);
                    }
                } else {
                    const int d = col - DIq;
                    #pragma unroll
                    for (int r = 0; r < 4; ++r) {
                        int row = r0 + r;
                        if (row < Lq) {
                            float v = c[r];
                            rs_lb[row][d] = f2b_tr(v * fast_rcp(1.f + __expf(-v)));
                        }
                    }
                }
            }
        }
        __syncthreads();

        // ---- C: depthwise causal conv (K=4) + bias + silu, in place ------
        {
            const float* cw = conv_w + (size_t)sl * (DIq * Kq);
            const int d = tid >> 1, half = tid & 1;
            const float c0 = cw[d*4+0], c1 = cw[d*4+1], c2 = cw[d*4+2], c3 = cw[d*4+3];
            const float cbv = conv_b[(size_t)sl * DIq + d];
            float w0 = 0.f, w1 = 0.f, w2 = 0.f;
            if (half) { w0 = b2f(u_lb[18][d]); w1 = b2f(u_lb[19][d]); w2 = b2f(u_lb[20][d]); }
            const int base = half ? 21 : 0;
            const int cnt  = half ? 20 : 21;
            for (int i = 0; i < cnt; ++i) {
                int l = base + i;
                float cur = b2f(u_lb[l][d]);
                float a = fmaf(w0, c0, fmaf(w1, c1, fmaf(w2, c2, fmaf(cur, c3, cbv))));
                u_lb[l][d] = f2b_tr(a * fast_rcp(1.f + __expf(-a)));
                w0 = w1; w1 = w2; w2 = cur;
            }
        }
        __syncthreads();

        // ---- D: dbl = u[48,128] @ xp[128,48] MFMA (keep cols<40) ---------
        {
            for (int t = wave; t < 9; t += 4) {
                const int mt = t / 3, ct = t % 3;
                int ar = mt * 16 + nl; if (ar > Lq - 1) ar = Lq - 1;
                f32x4 c = {0.f, 0.f, 0.f, 0.f};
                #pragma unroll
                for (int kt = 0; kt < 4; ++kt) {
                    frag8 a  = *(const frag8*)&u_lb[ar][kt * 32 + quad * 8];
                    frag8 bb = *(const frag8*)&xp_b[((size_t)(sl * 48 + ct * 16 + nl)) * 128 + kt * 32 + quad * 8];
                    c = __builtin_amdgcn_mfma_f32_16x16x32_bf16(a, bb, c, 0, 0, 0);
                }
                const int col = ct * 16 + nl, r0 = mt * 16 + quad * 4;
                if (col < 40) {
                    #pragma unroll
                    for (int r = 0; r < 4; ++r) {
                        int row = r0 + r;
                        if (row < Lq) dbl_s[row][col] = c[r];
                    }
                }
            }
        }
        __syncthreads();

        // ---- F: selective scan, fp32 state; z -> u_lb in place -----------
        // Paired softplus (dt shared by lane pair via shfl_xor); geometric
        // dA chain when Aflag[sl].
        {
            const int d = tid >> 1, half = tid & 1;
            const float* al = A_log + (size_t)sl * (DIq * Nq) + d * Nq + half * 8;
            float A2[8], h[8];
            #pragma unroll
            for (int n = 0; n < 8; ++n) {
                A2[n] = -__expf(al[n]) * 1.442695041f;   // fold log2(e) into A
                h[n] = 0.f;
            }
            const float dd = A2[1] - A2[0];
            const bool fastA = __builtin_amdgcn_readfirstlane(Aflag[sl]) != 0;
            const float* dw = dt_w + (size_t)sl * (DTRq * DIq);
            const float dw0 = dw[d], dw1 = dw[DIq + d], dw2 = dw[2*DIq + d], dw3 = dw[3*DIq + d];
            const float dbv = dt_b[(size_t)sl * DIq + d];
            const float dpd = Dp[(size_t)sl * DIq + d];

            auto step = [&](int l, float dt_) {
                float u_  = b2f(u_lb[l][d]);
                float4 B0 = *(const float4*)&dbl_s[l][4  + half * 8];
                float4 B1 = *(const float4*)&dbl_s[l][8  + half * 8];
                float4 C0 = *(const float4*)&dbl_s[l][20 + half * 8];
                float4 C1 = *(const float4*)&dbl_s[l][24 + half * 8];
                float dtu = dt_ * u_;
                float a0, a1, a2, a3, a4, a5, a6, a7;      // dA as named scalars
                if (fastA) {
                    a0 = __builtin_amdgcn_exp2f(dt_ * A2[0]);
                    float r = __builtin_amdgcn_exp2f(dt_ * dd);
                    a1 = a0 * r; a2 = a1 * r; a3 = a2 * r; a4 = a3 * r;
                    a5 = a4 * r; a6 = a5 * r; a7 = a6 * r;
                } else {
                    a0 = __builtin_amdgcn_exp2f(dt_ * A2[0]);
                    a1 = __builtin_amdgcn_exp2f(dt_ * A2[1]);
                    a2 = __builtin_amdgcn_exp2f(dt_ * A2[2]);
                    a3 = __builtin_amdgcn_exp2f(dt_ * A2[3]);
                    a4 = __builtin_amdgcn_exp2f(dt_ * A2[4]);
                    a5 = __builtin_amdgcn_exp2f(dt_ * A2[5]);
                    a6 = __builtin_amdgcn_exp2f(dt_ * A2[6]);
                    a7 = __builtin_amdgcn_exp2f(dt_ * A2[7]);
                }
                float y = 0.f;
                h[0] = fmaf(a0, h[0], B0.x * dtu); y = fmaf(h[0], C0.x, y);
                h[1] = fmaf(a1, h[1], B0.y * dtu); y = fmaf(h[1], C0.y, y);
                h[2] = fmaf(a2, h[2], B0.z * dtu); y = fmaf(h[2], C0.z, y);
                h[3] = fmaf(a3, h[3], B0.w * dtu); y = fmaf(h[3], C0.w, y);
                h[4] = fmaf(a4, h[4], B1.x * dtu); y = fmaf(h[4], C1.x, y);
                h[5] = fmaf(a5, h[5], B1.y * dtu); y = fmaf(h[5], C1.y, y);
                h[6] = fmaf(a6, h[6], B1.z * dtu); y = fmaf(h[6], C1.z, y);
                h[7] = fmaf(a7, h[7], B1.w * dtu); y = fmaf(h[7], C1.w, y);
                y += __shfl_xor(y, 1, 64);
                if (!half) {
                    float rsv = b2f(rs_lb[l][d]);
                    u_lb[l][d] = f2b_tr(fmaf(u_, dpd, y) * rsv);
                }
            };

            for (int l0 = 0; l0 < Lq; l0 += 2) {
                int lme = l0 + half; if (lme > Lq - 1) lme = Lq - 1;
                float4 q0 = *(const float4*)&dbl_s[lme][0];
                float x = fmaf(q0.x, dw0, fmaf(q0.y, dw1, fmaf(q0.z, dw2, fmaf(q0.w, dw3, dbv))));
                float dts = fmaxf(x, 0.f) + __logf(1.f + __expf(-fabsf(x)));
                float dto = __shfl_xor(dts, 1, 64);
                step(l0, half ? dto : dts);
                if (l0 + 1 < Lq) step(l0 + 1, half ? dts : dto);
            }
        }
        __syncthreads();

        // ---- G: xt += z[48,128] @ op[128,64] MFMA (LDS accumulate) -------
        {
            const int ntG = wave;
            for (int mt = 0; mt < 3; ++mt) {
                int ar = mt * 16 + nl; if (ar > Lq - 1) ar = Lq - 1;
                f32x4 c = {0.f, 0.f, 0.f, 0.f};
                #pragma unroll
                for (int kt = 0; kt < 4; ++kt) {
                    frag8 a  = *(const frag8*)&u_lb[ar][kt * 32 + quad * 8];
                    frag8 bb = *(const frag8*)&op_b[((size_t)(sl * 64 + ntG * 16 + nl)) * 128 + kt * 32 + quad * 8];
                    c = __builtin_amdgcn_mfma_f32_16x16x32_bf16(a, bb, c, 0, 0, 0);
                }
                const int j = ntG * 16 + nl, r0 = mt * 16 + quad * 4;
                #pragma unroll
                for (int r = 0; r < 4; ++r) {
                    int row = r0 + r;
                    if (row < Lq) xt[row][j] += c[r];
                }
            }
        }
        __syncthreads();
    }

    // ---- Epilogue: fused final rmsnorm + fusion weighting -> Xn bf16 -----
    {
        float fw0 = fusion_w[0], fw1 = fusion_w[1], fw2 = fusion_w[2];
        float mx = fmaxf(fw0, fmaxf(fw1, fw2));
        float e0 = __expf(fw0 - mx), e1 = __expf(fw1 - mx), e2 = __expf(fw2 - mx);
        float sw = (s == 0 ? e0 : (s == 1 ? e1 : e2)) * fast_rcp(e0 + e1 + e2);
        float nf = norm_f_w[lane] * sw;
        unsigned short* xr = Xn + ((size_t)s * Bq + b) * FLATq;
        for (int l = wave; l < Lq; l += 4) {
            float v  = xt[l][lane];
            float ss = v * v;
            #pragma unroll
            for (int off = 32; off; off >>= 1) ss += __shfl_xor(ss, off, 64);
            float scale = __builtin_amdgcn_rsqf(ss * (1.0f / Dq) + 1e-5f);
            xr[l * Dq + lane] = f2b_tr(v * scale * nf);
        }
    }
}

// ---------------------------------------------------------------------------
// head_gemm1: H1 = relu( (Σ_s Xn_s) @ W1 + b1 ). 192 blocks on 256 CUs ->
// single-block latency matters: 3 independent accumulators (c0/c1/c2, summed
// at the end) give 3x MFMA ILP (round-14: confirmed ~4 µs total win).
// ---------------------------------------------------------------------------
__global__ __launch_bounds__(256) void head_gemm1(const unsigned short* __restrict__ Xn,
                                                  const unsigned short* __restrict__ W1b,
                                                  const float* __restrict__ b1,
                                                  float* __restrict__ H1) {
    const int tid = threadIdx.x;
    const int wave = tid >> 6, lane = tid & 63;
    const int nl = lane & 15, quad = lane >> 4;
    const int mt = blockIdx.x, nt = blockIdx.y;

    __shared__ float red[4][16][17];

    const int kbeg = (wave < 2) ? wave * 21 : 42 + (wave - 2) * 20;
    const int kcnt = (wave < 2) ? 21 : 20;
    const size_t SB = (size_t)Bq * FLATq;
    const unsigned short* A0 = Xn  + (size_t)(mt * 16 + nl) * FLATq + quad * 8;
    const unsigned short* Br = W1b + (size_t)(nt * 16 + nl) * FLATq + quad * 8;

    f32x4 c0 = {0.f, 0.f, 0.f, 0.f};
    f32x4 c1 = {0.f, 0.f, 0.f, 0.f};
    f32x4 c2 = {0.f, 0.f, 0.f, 0.f};
    for (int ks = kbeg; ks < kbeg + kcnt; ++ks) {
        const int off = ks * 32;
        frag8 bb = *(const frag8*)(Br + off);
        frag8 a0 = *(const frag8*)(A0 + off);
        frag8 a1 = *(const frag8*)(A0 + SB + off);
        frag8 a2 = *(const frag8*)(A0 + 2 * SB + off);
        c0 = __builtin_amdgcn_mfma_f32_16x16x32_bf16(a0, bb, c0, 0, 0, 0);
        c1 = __builtin_amdgcn_mfma_f32_16x16x32_bf16(a1, bb, c1, 0, 0, 0);
        c2 = __builtin_amdgcn_mfma_f32_16x16x32_bf16(a2, bb, c2, 0, 0, 0);
    }
    #pragma unroll
    for (int r = 0; r < 4; ++r) red[wave][quad * 4 + r][nl] = c0[r] + c1[r] + c2[r];
    __syncthreads();

    const int row = tid >> 4, colv = tid & 15;
    float acc = red[0][row][colv] + red[1][row][colv]
              + red[2][row][colv] + red[3][row][colv];
    const int col = nt * 16 + colv;
    H1[(size_t)(mt * 16 + row) * H1q + col] = fmaxf(acc + b1[col], 0.f);
}

// ---------------------------------------------------------------------------
// head_final: h2 = relu(H1@W2+b2); out = sigmoid(h2@W3+b3). 16 batches/block.
// ---------------------------------------------------------------------------
__global__ __launch_bounds__(256) void head_final(const float* __restrict__ H1,
                                                  const float* __restrict__ W2,
                                                  const float* __restrict__ b2,
                                                  const float* __restrict__ W3,
                                                  const float* __restrict__ b3,
                                                  float* __restrict__ out) {
    const int b0 = blockIdx.x * 16, tid = threadIdx.x;
    __shared__ float H1s[16 * H1q];
    __shared__ float h2s[16][16];
    for (int idx = tid; idx < 16 * H1q; idx += 256)
        H1s[idx] = H1[(size_t)b0 * H1q + idx];
    __syncthreads();
    {
        const int row = tid >> 4, g = tid & 15;
        float acc = b2[g];
        for (int k = 0; k < H1q; ++k)
            acc = fmaf(H1s[row * H1q + k], W2[k * H2q + g], acc);
        h2s[row][g] = fmaxf(acc, 0.f);
    }
    __syncthreads();
    if (tid < 16) {
        float z = b3[0];
        #pragma unroll
        for (int k = 0; k < H2q; ++k) z = fmaf(h2s[tid][k], W3[k], z);
        out[b0 + tid] = fast_rcp(1.f + __expf(-z));
    }
}

// ---------------------------------------------------------------------------
extern "C" void kernel_launch(void* const* d_in, const int* in_sizes, int n_in,
                              void* d_out, int out_size, void* d_ws, size_t ws_size,
                              hipStream_t stream) {
    const int*   ids      = (const int*)  d_in[0];
    const float* emb      = (const float*)d_in[1];
    const float* in_proj  = (const float*)d_in[2];
    const float* conv_w   = (const float*)d_in[3];
    const float* conv_b   = (const float*)d_in[4];
    const float* x_proj   = (const float*)d_in[5];
    const float* dt_w     = (const float*)d_in[6];
    const float* dt_b     = (const float*)d_in[7];
    const float* A_log    = (const float*)d_in[8];
    const float* Dp       = (const float*)d_in[9];
    const float* out_proj = (const float*)d_in[10];
    const float* norm_w   = (const float*)d_in[11];
    const float* norm_f_w = (const float*)d_in[12];
    const float* fusion_w = (const float*)d_in[13];
    const float* W1       = (const float*)d_in[14];
    const float* b1       = (const float*)d_in[15];
    const float* W2       = (const float*)d_in[16];
    const float* b2       = (const float*)d_in[17];
    const float* W3       = (const float*)d_in[18];
    const float* b3       = (const float*)d_in[19];
    float* out = (float*)d_out;

    // workspace (shorts unless noted):
    //   Xn    3*512*2624 = 4,030,464
    //   Wb_in   147,456 | xp_b 55,296 | op_b 73,728 | W1b 1,007,616
    //   H1 (fp32) 512*384 = 196,608 floats
    //   Aflag: aliased onto the first 9 ints of H1 (prep writes, mamba_stack
    //   reads, head_gemm1 overwrites H1 only after mamba_stack completes).
    unsigned short* Xn    = (unsigned short*)d_ws;
    unsigned short* Wb_in = Xn    + (size_t)NSq * Bq * FLATq;
    unsigned short* xp_b  = Wb_in + 9*256*64;
    unsigned short* op_b  = xp_b  + 9*48*128;
    unsigned short* W1b   = op_b  + 9*64*128;
    float*          H1    = (float*)(W1b + (size_t)H1q * FLATq);
    int*            Aflag = (int*)H1;

    hipLaunchKernelGGL(prep_kernel, dim3(246 + 1080 + 1), dim3(256), 0, stream,
                       W1, in_proj, x_proj, out_proj, A_log, W1b, Wb_in, xp_b, op_b, Aflag);

    hipLaunchKernelGGL(mamba_stack, dim3(Bq, NSq), dim3(256), 0, stream,
                       Xn, ids, emb, Wb_in, conv_w, conv_b, xp_b, dt_w, dt_b,
                       A_log, Dp, op_b, norm_w, norm_f_w, fusion_w, Aflag);

    hipLaunchKernelGGL(head_gemm1, dim3(Bq/16, H1q/64), dim3(256), 0, stream,
                       Xn, W1b, b1, H1);

    hipLaunchKernelGGL(head_final, dim3(Bq/16), dim3(256), 0, stream,
                       H1, W2, b2, W3, b3, out);
}

// Round 19
// 295.123 us; speedup vs baseline: 1.1825x; 1.0002x over previous
//
#include <hip/hip_runtime.h>
#include <hip/hip_bf16.h>
#include <math.h>

// Problem constants
#define Bq  512
#define Lq  41
#define Vq  4
#define Dq  64
#define NLq 3
#define DIq 128
#define Nq  16
#define DTRq 4
#define Kq  4
#define NSq 3
#define H1q 384
#define H2q 16
#define FLATq (Lq*Dq)   // 2624

typedef __attribute__((ext_vector_type(8))) short frag8;   // 8 bf16 (4 VGPRs)
typedef __attribute__((ext_vector_type(4))) float f32x4;

__device__ __forceinline__ float b2f(unsigned short u) {
    union { float f; unsigned int i; } v; v.i = ((unsigned int)u) << 16; return v.f;
}
__device__ __forceinline__ unsigned short f2b_rne(float f) {
    union { float f; unsigned int i; } v; v.f = f;
    unsigned int x = v.i;
    return (unsigned short)((x + 0x7fffu + ((x >> 16) & 1u)) >> 16);
}
__device__ __forceinline__ unsigned short f2b_tr(float f) {
    union { float f; unsigned int i; } v; v.f = f;
    return (unsigned short)(v.i >> 16);
}
__device__ __forceinline__ float fast_rcp(float x) { return __builtin_amdgcn_rcpf(x); }

// ---------------------------------------------------------------------------
// prep: blocks [0,246) transpose W1 -> W1b bf16 [384][2624];
//       blocks [246,1326) convert/transpose small weights;
//       block 1326 checks A-delta uniformity per (s,layer) -> Aflag[9]
//       (enables geometric-chain dA in the scan; falls back if not uniform).
// ---------------------------------------------------------------------------
__global__ __launch_bounds__(256) void prep_kernel(const float* __restrict__ W1,
                                                   const float* __restrict__ in_proj,
                                                   const float* __restrict__ x_proj,
                                                   const float* __restrict__ out_proj,
                                                   const float* __restrict__ A_log,
                                                   unsigned short* __restrict__ W1b,
                                                   unsigned short* __restrict__ Wb_in,
                                                   unsigned short* __restrict__ xp_b,
                                                   unsigned short* __restrict__ op_b,
                                                   int* __restrict__ Aflag) {
    const int bx = blockIdx.x;
    if (bx < 246) {
        __shared__ float t[64][65];
        const int k0 = (bx / 6) * 64, n0 = (bx % 6) * 64;
        for (int idx = threadIdx.x; idx < 4096; idx += 256) {
            int kr = idx >> 6, nc = idx & 63;
            t[kr][nc] = W1[(size_t)(k0 + kr) * H1q + n0 + nc];
        }
        __syncthreads();
        for (int idx = threadIdx.x; idx < 4096; idx += 256) {
            int nr = idx >> 6, kc = idx & 63;
            W1b[(size_t)(n0 + nr) * FLATq + k0 + kc] = f2b_rne(t[kc][nr]);
        }
        return;
    }
    if (bx == 246 + 1080) {
        // A-structure uniformity flags: for each sl, check that within every
        // (d, half) 8-state group, A[n+1]-A[n] is constant (A = -exp(A_log)).
        const int tid = threadIdx.x;
        const int d = tid >> 1, half = tid & 1;
        for (int sl = 0; sl < 9; ++sl) {
            const float* al = A_log + (size_t)sl * (DIq * Nq) + d * Nq + half * 8;
            float A2[8];
            #pragma unroll
            for (int n = 0; n < 8; ++n) A2[n] = -__expf(al[n]);
            float d0 = A2[1] - A2[0];
            int ok = 1;
            #pragma unroll
            for (int n = 2; n < 8; ++n) {
                float dk = A2[n] - A2[n-1];
                if (!(fabsf(dk - d0) <= 1e-4f * fabsf(d0) + 1e-12f)) ok = 0;
            }
            int allok = __syncthreads_and(ok);
            if (tid == 0) Aflag[sl] = allok;
        }
        return;
    }
    int idx = (bx - 246) * 256 + threadIdx.x;
    if (idx < 9*256*64) {
        int sl = idx >> 14, rem = idx & 16383;
        int n = rem >> 6, k = rem & 63;
        Wb_in[idx] = f2b_rne(in_proj[(size_t)sl*16384 + k*256 + n]);
    } else if (idx < 9*256*64 + 9*48*128) {
        int i2 = idx - 9*256*64;
        int sl = i2 / 6144, rem = i2 % 6144;
        int c = rem >> 7, k = rem & 127;
        float v = (c < 36) ? x_proj[(size_t)sl*(128*36) + k*36 + c] : 0.f;
        xp_b[i2] = f2b_rne(v);
    } else if (idx < 9*256*64 + 9*48*128 + 9*64*128) {
        int i3 = idx - (9*256*64 + 9*48*128);
        int sl = i3 >> 13, rem = i3 & 8191;
        int n = rem >> 7, k = rem & 127;
        op_b[i3] = f2b_rne(out_proj[(size_t)sl*8192 + k*64 + n]);
    }
}

// ---------------------------------------------------------------------------
// mamba_stack: ALL 3 layers for one (s,b), residual kept in LDS.
// BEST-MEASURED configuration (r14: 292.5 µs total, r18: 295.2 — reproduced):
// 256 threads, __launch_bounds__(256,2) (relaxed VGPR budget — (256,4) pinned
// 64 VGPR and spilled 24 f32/thread), xt stride 76 (bank-conflict fix),
// scalar dA chain, paired softplus, no sched fences.
// Falsified alternatives (measured): 8-wave blocks (r13: +20%), register
// rotation (r16: +25%), fences (r10: null), residency shaping (r8/r9: null).
// LDS: xt 12464 (stride 76) + u 11152 + rs 10824 + union{xn|dbl} 6560 = 41000 B
// ---------------------------------------------------------------------------
__global__ __launch_bounds__(256, 2) void mamba_stack(
    unsigned short* __restrict__ Xn,            // [NS][B][FLAT] bf16 OUTPUT
    const int* __restrict__ ids,
    const float* __restrict__ emb,
    const unsigned short* __restrict__ Wb_in,   // [9][256][64]
    const float* __restrict__ conv_w,
    const float* __restrict__ conv_b,
    const unsigned short* __restrict__ xp_b,    // [9][48][128]
    const float* __restrict__ dt_w,
    const float* __restrict__ dt_b,
    const float* __restrict__ A_log,
    const float* __restrict__ Dp,
    const unsigned short* __restrict__ op_b,    // [9][64][128]
    const float* __restrict__ norm_w,
    const float* __restrict__ norm_f_w,
    const float* __restrict__ fusion_w,
    const int* __restrict__ Aflag)              // [9] uniform-A flags
{
    const int b = blockIdx.x, s = blockIdx.y, tid = threadIdx.x;
    const int wave = tid >> 6, lane = tid & 63;
    const int nl = lane & 15, quad = lane >> 4;

    __shared__ float          xt  [Lq][76];     // residual stream (fp32), stride 76
    __shared__ unsigned short u_lb[Lq][136];    // bf16 u; z in place after scan
    __shared__ unsigned short rs_lb[Lq][132];   // bf16 silu(res)
    __shared__ __align__(16) char un_buf[6560]; // union: xn (A->B) | dbl (D->F)
    unsigned short (*xn_lb)[72] = (unsigned short(*)[72])un_buf;
    float          (*dbl_s)[40] = (float(*)[40])un_buf;

    // ---- residual init from embedding (layer 0) --------------------------
    for (int l = wave; l < Lq; l += 4) {
        int id = ids[b * Lq + l];
        xt[l][lane] = emb[id * Dq + lane];
    }

    for (int layer = 0; layer < NLq; ++layer) {
        const int sl = s * NLq + layer;

        // ---- A: rmsnorm(xt) -> xn bf16 -----------------------------------
        {
            const float nwv = norm_w[(size_t)sl * Dq + lane];
            for (int l = wave; l < Lq; l += 4) {
                float v  = xt[l][lane];
                float ss = v * v;
                #pragma unroll
                for (int off = 32; off; off >>= 1) ss += __shfl_xor(ss, off, 64);
                float scale = __builtin_amdgcn_rsqf(ss * (1.0f / Dq) + 1e-5f);
                xn_lb[l][lane] = f2b_tr(v * scale * nwv);
            }
        }
        __syncthreads();

        // ---- B: [48,64]@[64,256] MFMA -> u (cols<128), silu -> rs --------
        {
            #pragma unroll
            for (int t = 0; t < 12; ++t) {
                const int id = wave * 12 + t;
                const int mt = id >> 4, nt = id & 15;
                int ar = mt * 16 + nl; if (ar > Lq - 1) ar = Lq - 1;   // rows>40: clamp, output discarded
                const unsigned short* Wp = Wb_in + ((size_t)(sl * 256 + nt * 16 + nl)) * 64 + quad * 8;
                frag8 a0 = *(const frag8*)&xn_lb[ar][quad * 8];
                frag8 a1 = *(const frag8*)&xn_lb[ar][32 + quad * 8];
                frag8 b0 = *(const frag8*)&Wp[0];
                frag8 b1 = *(const frag8*)&Wp[32];
                f32x4 c = {0.f, 0.f, 0.f, 0.f};
                c = __builtin_amdgcn_mfma_f32_16x16x32_bf16(a0, b0, c, 0, 0, 0);
                c = __builtin_amdgcn_mfma_f32_16x16x32_bf16(a1, b1, c, 0, 0, 0);
                const int col = nt * 16 + nl;
                const int r0 = mt * 16 + quad * 4;
                if (col < DIq) {
                    #pragma unroll
                    for (int r = 0; r < 4; ++r) {
                        int row = r0 + r;
                        if (row < Lq) u_lb[row][col] = f2b_tr(c[r]);
                    }
                } else {
                    const int d = col - DIq;
                    #pragma unroll
                    for (int r = 0; r < 4; ++r) {
                        int row = r0 + r;
                        if (row < Lq) {
                            float v = c[r];
                            rs_lb[row][d] = f2b_tr(v * fast_rcp(1.f + __expf(-v)));
                        }
                    }
                }
            }
        }
        __syncthreads();

        // ---- C: depthwise causal conv (K=4) + bias + silu, in place ------
        {
            const float* cw = conv_w + (size_t)sl * (DIq * Kq);
            const int d = tid >> 1, half = tid & 1;
            const float c0 = cw[d*4+0], c1 = cw[d*4+1], c2 = cw[d*4+2], c3 = cw[d*4+3];
            const float cbv = conv_b[(size_t)sl * DIq + d];
            float w0 = 0.f, w1 = 0.f, w2 = 0.f;
            if (half) { w0 = b2f(u_lb[18][d]); w1 = b2f(u_lb[19][d]); w2 = b2f(u_lb[20][d]); }
            const int base = half ? 21 : 0;
            const int cnt  = half ? 20 : 21;
            for (int i = 0; i < cnt; ++i) {
                int l = base + i;
                float cur = b2f(u_lb[l][d]);
                float a = fmaf(w0, c0, fmaf(w1, c1, fmaf(w2, c2, fmaf(cur, c3, cbv))));
                u_lb[l][d] = f2b_tr(a * fast_rcp(1.f + __expf(-a)));
                w0 = w1; w1 = w2; w2 = cur;
            }
        }
        __syncthreads();

        // ---- D: dbl = u[48,128] @ xp[128,48] MFMA (keep cols<40) ---------
        {
            for (int t = wave; t < 9; t += 4) {
                const int mt = t / 3, ct = t % 3;
                int ar = mt * 16 + nl; if (ar > Lq - 1) ar = Lq - 1;
                f32x4 c = {0.f, 0.f, 0.f, 0.f};
                #pragma unroll
                for (int kt = 0; kt < 4; ++kt) {
                    frag8 a  = *(const frag8*)&u_lb[ar][kt * 32 + quad * 8];
                    frag8 bb = *(const frag8*)&xp_b[((size_t)(sl * 48 + ct * 16 + nl)) * 128 + kt * 32 + quad * 8];
                    c = __builtin_amdgcn_mfma_f32_16x16x32_bf16(a, bb, c, 0, 0, 0);
                }
                const int col = ct * 16 + nl, r0 = mt * 16 + quad * 4;
                if (col < 40) {
                    #pragma unroll
                    for (int r = 0; r < 4; ++r) {
                        int row = r0 + r;
                        if (row < Lq) dbl_s[row][col] = c[r];
                    }
                }
            }
        }
        __syncthreads();

        // ---- F: selective scan, fp32 state; z -> u_lb in place -----------
        // Paired softplus (dt shared by lane pair via shfl_xor); geometric
        // dA chain when Aflag[sl].
        {
            const int d = tid >> 1, half = tid & 1;
            const float* al = A_log + (size_t)sl * (DIq * Nq) + d * Nq + half * 8;
            float A2[8], h[8];
            #pragma unroll
            for (int n = 0; n < 8; ++n) {
                A2[n] = -__expf(al[n]) * 1.442695041f;   // fold log2(e) into A
                h[n] = 0.f;
            }
            const float dd = A2[1] - A2[0];
            const bool fastA = __builtin_amdgcn_readfirstlane(Aflag[sl]) != 0;
            const float* dw = dt_w + (size_t)sl * (DTRq * DIq);
            const float dw0 = dw[d], dw1 = dw[DIq + d], dw2 = dw[2*DIq + d], dw3 = dw[3*DIq + d];
            const float dbv = dt_b[(size_t)sl * DIq + d];
            const float dpd = Dp[(size_t)sl * DIq + d];

            auto step = [&](int l, float dt_) {
                float u_  = b2f(u_lb[l][d]);
                float4 B0 = *(const float4*)&dbl_s[l][4  + half * 8];
                float4 B1 = *(const float4*)&dbl_s[l][8  + half * 8];
                float4 C0 = *(const float4*)&dbl_s[l][20 + half * 8];
                float4 C1 = *(const float4*)&dbl_s[l][24 + half * 8];
                float dtu = dt_ * u_;
                float a0, a1, a2, a3, a4, a5, a6, a7;      // dA as named scalars
                if (fastA) {
                    a0 = __builtin_amdgcn_exp2f(dt_ * A2[0]);
                    float r = __builtin_amdgcn_exp2f(dt_ * dd);
                    a1 = a0 * r; a2 = a1 * r; a3 = a2 * r; a4 = a3 * r;
                    a5 = a4 * r; a6 = a5 * r; a7 = a6 * r;
                } else {
                    a0 = __builtin_amdgcn_exp2f(dt_ * A2[0]);
                    a1 = __builtin_amdgcn_exp2f(dt_ * A2[1]);
                    a2 = __builtin_amdgcn_exp2f(dt_ * A2[2]);
                    a3 = __builtin_amdgcn_exp2f(dt_ * A2[3]);
                    a4 = __builtin_amdgcn_exp2f(dt_ * A2[4]);
                    a5 = __builtin_amdgcn_exp2f(dt_ * A2[5]);
                    a6 = __builtin_amdgcn_exp2f(dt_ * A2[6]);
                    a7 = __builtin_amdgcn_exp2f(dt_ * A2[7]);
                }
                float y = 0.f;
                h[0] = fmaf(a0, h[0], B0.x * dtu); y = fmaf(h[0], C0.x, y);
                h[1] = fmaf(a1, h[1], B0.y * dtu); y = fmaf(h[1], C0.y, y);
                h[2] = fmaf(a2, h[2], B0.z * dtu); y = fmaf(h[2], C0.z, y);
                h[3] = fmaf(a3, h[3], B0.w * dtu); y = fmaf(h[3], C0.w, y);
                h[4] = fmaf(a4, h[4], B1.x * dtu); y = fmaf(h[4], C1.x, y);
                h[5] = fmaf(a5, h[5], B1.y * dtu); y = fmaf(h[5], C1.y, y);
                h[6] = fmaf(a6, h[6], B1.z * dtu); y = fmaf(h[6], C1.z, y);
                h[7] = fmaf(a7, h[7], B1.w * dtu); y = fmaf(h[7], C1.w, y);
                y += __shfl_xor(y, 1, 64);
                if (!half) {
                    float rsv = b2f(rs_lb[l][d]);
                    u_lb[l][d] = f2b_tr(fmaf(u_, dpd, y) * rsv);
                }
            };

            for (int l0 = 0; l0 < Lq; l0 += 2) {
                int lme = l0 + half; if (lme > Lq - 1) lme = Lq - 1;
                float4 q0 = *(const float4*)&dbl_s[lme][0];
                float x = fmaf(q0.x, dw0, fmaf(q0.y, dw1, fmaf(q0.z, dw2, fmaf(q0.w, dw3, dbv))));
                float dts = fmaxf(x, 0.f) + __logf(1.f + __expf(-fabsf(x)));
                float dto = __shfl_xor(dts, 1, 64);
                step(l0, half ? dto : dts);
                if (l0 + 1 < Lq) step(l0 + 1, half ? dts : dto);
            }
        }
        __syncthreads();

        // ---- G: xt += z[48,128] @ op[128,64] MFMA (LDS accumulate) -------
        {
            const int ntG = wave;
            for (int mt = 0; mt < 3; ++mt) {
                int ar = mt * 16 + nl; if (ar > Lq - 1) ar = Lq - 1;
                f32x4 c = {0.f, 0.f, 0.f, 0.f};
                #pragma unroll
                for (int kt = 0; kt < 4; ++kt) {
                    frag8 a  = *(const frag8*)&u_lb[ar][kt * 32 + quad * 8];
                    frag8 bb = *(const frag8*)&op_b[((size_t)(sl * 64 + ntG * 16 + nl)) * 128 + kt * 32 + quad * 8];
                    c = __builtin_amdgcn_mfma_f32_16x16x32_bf16(a, bb, c, 0, 0, 0);
                }
                const int j = ntG * 16 + nl, r0 = mt * 16 + quad * 4;
                #pragma unroll
                for (int r = 0; r < 4; ++r) {
                    int row = r0 + r;
                    if (row < Lq) xt[row][j] += c[r];
                }
            }
        }
        __syncthreads();
    }

    // ---- Epilogue: fused final rmsnorm + fusion weighting -> Xn bf16 -----
    {
        float fw0 = fusion_w[0], fw1 = fusion_w[1], fw2 = fusion_w[2];
        float mx = fmaxf(fw0, fmaxf(fw1, fw2));
        float e0 = __expf(fw0 - mx), e1 = __expf(fw1 - mx), e2 = __expf(fw2 - mx);
        float sw = (s == 0 ? e0 : (s == 1 ? e1 : e2)) * fast_rcp(e0 + e1 + e2);
        float nf = norm_f_w[lane] * sw;
        unsigned short* xr = Xn + ((size_t)s * Bq + b) * FLATq;
        for (int l = wave; l < Lq; l += 4) {
            float v  = xt[l][lane];
            float ss = v * v;
            #pragma unroll
            for (int off = 32; off; off >>= 1) ss += __shfl_xor(ss, off, 64);
            float scale = __builtin_amdgcn_rsqf(ss * (1.0f / Dq) + 1e-5f);
            xr[l * Dq + lane] = f2b_tr(v * scale * nf);
        }
    }
}

// ---------------------------------------------------------------------------
// head_gemm1: H1 = relu( (Σ_s Xn_s) @ W1 + b1 ). 192 blocks on 256 CUs ->
// single-block latency matters: 3 independent accumulators (c0/c1/c2, summed
// at the end) give 3x MFMA ILP (round-14: confirmed ~4 µs total win).
// ---------------------------------------------------------------------------
__global__ __launch_bounds__(256) void head_gemm1(const unsigned short* __restrict__ Xn,
                                                  const unsigned short* __restrict__ W1b,
                                                  const float* __restrict__ b1,
                                                  float* __restrict__ H1) {
    const int tid = threadIdx.x;
    const int wave = tid >> 6, lane = tid & 63;
    const int nl = lane & 15, quad = lane >> 4;
    const int mt = blockIdx.x, nt = blockIdx.y;

    __shared__ float red[4][16][17];

    const int kbeg = (wave < 2) ? wave * 21 : 42 + (wave - 2) * 20;
    const int kcnt = (wave < 2) ? 21 : 20;
    const size_t SB = (size_t)Bq * FLATq;
    const unsigned short* A0 = Xn  + (size_t)(mt * 16 + nl) * FLATq + quad * 8;
    const unsigned short* Br = W1b + (size_t)(nt * 16 + nl) * FLATq + quad * 8;

    f32x4 c0 = {0.f, 0.f, 0.f, 0.f};
    f32x4 c1 = {0.f, 0.f, 0.f, 0.f};
    f32x4 c2 = {0.f, 0.f, 0.f, 0.f};
    for (int ks = kbeg; ks < kbeg + kcnt; ++ks) {
        const int off = ks * 32;
        frag8 bb = *(const frag8*)(Br + off);
        frag8 a0 = *(const frag8*)(A0 + off);
        frag8 a1 = *(const frag8*)(A0 + SB + off);
        frag8 a2 = *(const frag8*)(A0 + 2 * SB + off);
        c0 = __builtin_amdgcn_mfma_f32_16x16x32_bf16(a0, bb, c0, 0, 0, 0);
        c1 = __builtin_amdgcn_mfma_f32_16x16x32_bf16(a1, bb, c1, 0, 0, 0);
        c2 = __builtin_amdgcn_mfma_f32_16x16x32_bf16(a2, bb, c2, 0, 0, 0);
    }
    #pragma unroll
    for (int r = 0; r < 4; ++r) red[wave][quad * 4 + r][nl] = c0[r] + c1[r] + c2[r];
    __syncthreads();

    const int row = tid >> 4, colv = tid & 15;
    float acc = red[0][row][colv] + red[1][row][colv]
              + red[2][row][colv] + red[3][row][colv];
    const int col = nt * 16 + colv;
    H1[(size_t)(mt * 16 + row) * H1q + col] = fmaxf(acc + b1[col], 0.f);
}

// ---------------------------------------------------------------------------
// head_final: h2 = relu(H1@W2+b2); out = sigmoid(h2@W3+b3). 16 batches/block.
// ---------------------------------------------------------------------------
__global__ __launch_bounds__(256) void head_final(const float* __restrict__ H1,
                                                  const float* __restrict__ W2,
                                                  const float* __restrict__ b2,
                                                  const float* __restrict__ W3,
                                                  const float* __restrict__ b3,
                                                  float* __restrict__ out) {
    const int b0 = blockIdx.x * 16, tid = threadIdx.x;
    __shared__ float H1s[16 * H1q];
    __shared__ float h2s[16][16];
    for (int idx = tid; idx < 16 * H1q; idx += 256)
        H1s[idx] = H1[(size_t)b0 * H1q + idx];
    __syncthreads();
    {
        const int row = tid >> 4, g = tid & 15;
        float acc = b2[g];
        for (int k = 0; k < H1q; ++k)
            acc = fmaf(H1s[row * H1q + k], W2[k * H2q + g], acc);
        h2s[row][g] = fmaxf(acc, 0.f);
    }
    __syncthreads();
    if (tid < 16) {
        float z = b3[0];
        #pragma unroll
        for (int k = 0; k < H2q; ++k) z = fmaf(h2s[tid][k], W3[k], z);
        out[b0 + tid] = fast_rcp(1.f + __expf(-z));
    }
}

// ---------------------------------------------------------------------------
extern "C" void kernel_launch(void* const* d_in, const int* in_sizes, int n_in,
                              void* d_out, int out_size, void* d_ws, size_t ws_size,
                              hipStream_t stream) {
    const int*   ids      = (const int*)  d_in[0];
    const float* emb      = (const float*)d_in[1];
    const float* in_proj  = (const float*)d_in[2];
    const float* conv_w   = (const float*)d_in[3];
    const float* conv_b   = (const float*)d_in[4];
    const float* x_proj   = (const float*)d_in[5];
    const float* dt_w     = (const float*)d_in[6];
    const float* dt_b     = (const float*)d_in[7];
    const float* A_log    = (const float*)d_in[8];
    const float* Dp       = (const float*)d_in[9];
    const float* out_proj = (const float*)d_in[10];
    const float* norm_w   = (const float*)d_in[11];
    const float* norm_f_w = (const float*)d_in[12];
    const float* fusion_w = (const float*)d_in[13];
    const float* W1       = (const float*)d_in[14];
    const float* b1       = (const float*)d_in[15];
    const float* W2       = (const float*)d_in[16];
    const float* b2       = (const float*)d_in[17];
    const float* W3       = (const float*)d_in[18];
    const float* b3       = (const float*)d_in[19];
    float* out = (float*)d_out;

    // workspace (shorts unless noted):
    //   Xn    3*512*2624 = 4,030,464
    //   Wb_in   147,456 | xp_b 55,296 | op_b 73,728 | W1b 1,007,616
    //   H1 (fp32) 512*384 = 196,608 floats
    //   Aflag: aliased onto the first 9 ints of H1 (prep writes, mamba_stack
    //   reads, head_gemm1 overwrites H1 only after mamba_stack completes).
    unsigned short* Xn    = (unsigned short*)d_ws;
    unsigned short* Wb_in = Xn    + (size_t)NSq * Bq * FLATq;
    unsigned short* xp_b  = Wb_in + 9*256*64;
    unsigned short* op_b  = xp_b  + 9*48*128;
    unsigned short* W1b   = op_b  + 9*64*128;
    float*          H1    = (float*)(W1b + (size_t)H1q * FLATq);
    int*            Aflag = (int*)H1;

    hipLaunchKernelGGL(prep_kernel, dim3(246 + 1080 + 1), dim3(256), 0, stream,
                       W1, in_proj, x_proj, out_proj, A_log, W1b, Wb_in, xp_b, op_b, Aflag);

    hipLaunchKernelGGL(mamba_stack, dim3(Bq, NSq), dim3(256), 0, stream,
                       Xn, ids, emb, Wb_in, conv_w, conv_b, xp_b, dt_w, dt_b,
                       A_log, Dp, op_b, norm_w, norm_f_w, fusion_w, Aflag);

    hipLaunchKernelGGL(head_gemm1, dim3(Bq/16, H1q/64), dim3(256), 0, stream,
                       Xn, W1b, b1, H1);

    hipLaunchKernelGGL(head_final, dim3(Bq/16), dim3(256), 0, stream,
                       H1, W2, b2, W3, b3, out);
}

// Round 20
// 291.201 us; speedup vs baseline: 1.1984x; 1.0135x over previous
//
#include <hip/hip_runtime.h>
#include <hip/hip_bf16.h>
#include <math.h>

// Problem constants
#define Bq  512
#define Lq  41
#define Vq  4
#define Dq  64
#define NLq 3
#define DIq 128
#define Nq  16
#define DTRq 4
#define Kq  4
#define NSq 3
#define H1q 384
#define H2q 16
#define FLATq (Lq*Dq)   // 2624

typedef __attribute__((ext_vector_type(8))) short frag8;   // 8 bf16 (4 VGPRs)
typedef __attribute__((ext_vector_type(4))) float f32x4;

__device__ __forceinline__ float b2f(unsigned short u) {
    union { float f; unsigned int i; } v; v.i = ((unsigned int)u) << 16; return v.f;
}
__device__ __forceinline__ unsigned short f2b_rne(float f) {
    union { float f; unsigned int i; } v; v.f = f;
    unsigned int x = v.i;
    return (unsigned short)((x + 0x7fffu + ((x >> 16) & 1u)) >> 16);
}
__device__ __forceinline__ unsigned short f2b_tr(float f) {
    union { float f; unsigned int i; } v; v.f = f;
    return (unsigned short)(v.i >> 16);
}
__device__ __forceinline__ float fast_rcp(float x) { return __builtin_amdgcn_rcpf(x); }

// ---------------------------------------------------------------------------
// prep: blocks [0,246) transpose W1 -> W1b bf16 [384][2624];
//       blocks [246,1326) convert/transpose small weights;
//       block 1326 checks A-delta uniformity per (s,layer) -> Aflag[9]
//       (enables geometric-chain dA in the scan; falls back if not uniform).
// ---------------------------------------------------------------------------
__global__ __launch_bounds__(256) void prep_kernel(const float* __restrict__ W1,
                                                   const float* __restrict__ in_proj,
                                                   const float* __restrict__ x_proj,
                                                   const float* __restrict__ out_proj,
                                                   const float* __restrict__ A_log,
                                                   unsigned short* __restrict__ W1b,
                                                   unsigned short* __restrict__ Wb_in,
                                                   unsigned short* __restrict__ xp_b,
                                                   unsigned short* __restrict__ op_b,
                                                   int* __restrict__ Aflag) {
    const int bx = blockIdx.x;
    if (bx < 246) {
        __shared__ float t[64][65];
        const int k0 = (bx / 6) * 64, n0 = (bx % 6) * 64;
        for (int idx = threadIdx.x; idx < 4096; idx += 256) {
            int kr = idx >> 6, nc = idx & 63;
            t[kr][nc] = W1[(size_t)(k0 + kr) * H1q + n0 + nc];
        }
        __syncthreads();
        for (int idx = threadIdx.x; idx < 4096; idx += 256) {
            int nr = idx >> 6, kc = idx & 63;
            W1b[(size_t)(n0 + nr) * FLATq + k0 + kc] = f2b_rne(t[kc][nr]);
        }
        return;
    }
    if (bx == 246 + 1080) {
        // A-structure uniformity flags: for each sl, check that within every
        // (d, half) 8-state group, A[n+1]-A[n] is constant (A = -exp(A_log)).
        const int tid = threadIdx.x;
        const int d = tid >> 1, half = tid & 1;
        for (int sl = 0; sl < 9; ++sl) {
            const float* al = A_log + (size_t)sl * (DIq * Nq) + d * Nq + half * 8;
            float A2[8];
            #pragma unroll
            for (int n = 0; n < 8; ++n) A2[n] = -__expf(al[n]);
            float d0 = A2[1] - A2[0];
            int ok = 1;
            #pragma unroll
            for (int n = 2; n < 8; ++n) {
                float dk = A2[n] - A2[n-1];
                if (!(fabsf(dk - d0) <= 1e-4f * fabsf(d0) + 1e-12f)) ok = 0;
            }
            int allok = __syncthreads_and(ok);
            if (tid == 0) Aflag[sl] = allok;
        }
        return;
    }
    int idx = (bx - 246) * 256 + threadIdx.x;
    if (idx < 9*256*64) {
        int sl = idx >> 14, rem = idx & 16383;
        int n = rem >> 6, k = rem & 63;
        Wb_in[idx] = f2b_rne(in_proj[(size_t)sl*16384 + k*256 + n]);
    } else if (idx < 9*256*64 + 9*48*128) {
        int i2 = idx - 9*256*64;
        int sl = i2 / 6144, rem = i2 % 6144;
        int c = rem >> 7, k = rem & 127;
        float v = (c < 36) ? x_proj[(size_t)sl*(128*36) + k*36 + c] : 0.f;
        xp_b[i2] = f2b_rne(v);
    } else if (idx < 9*256*64 + 9*48*128 + 9*64*128) {
        int i3 = idx - (9*256*64 + 9*48*128);
        int sl = i3 >> 13, rem = i3 & 8191;
        int n = rem >> 7, k = rem & 127;
        op_b[i3] = f2b_rne(out_proj[(size_t)sl*8192 + k*64 + n]);
    }
}

// ---------------------------------------------------------------------------
// mamba_stack: ALL 3 layers for one (s,b), residual kept in LDS.
// BEST-MEASURED configuration (r14: 292.5 µs total, r18: 295.2, r19: 295.1):
// 256 threads, __launch_bounds__(256,2) (relaxed VGPR budget — (256,4) pinned
// 64 VGPR and spilled 24 f32/thread), xt stride 76 (bank-conflict fix),
// scalar dA chain, paired softplus, no sched fences.
// Falsified alternatives (measured): 8-wave blocks (r13: +20%), register
// rotation (r16: +25%), fences (r10: null), residency shaping (r8/r9: null).
// Structural floor: 123-step serial scan chain between 21 barriers/block —
// invariant to occupancy/scheduling/pipelining at HIP source level.
// LDS: xt 12464 (stride 76) + u 11152 + rs 10824 + union{xn|dbl} 6560 = 41000 B
// ---------------------------------------------------------------------------
__global__ __launch_bounds__(256, 2) void mamba_stack(
    unsigned short* __restrict__ Xn,            // [NS][B][FLAT] bf16 OUTPUT
    const int* __restrict__ ids,
    const float* __restrict__ emb,
    const unsigned short* __restrict__ Wb_in,   // [9][256][64]
    const float* __restrict__ conv_w,
    const float* __restrict__ conv_b,
    const unsigned short* __restrict__ xp_b,    // [9][48][128]
    const float* __restrict__ dt_w,
    const float* __restrict__ dt_b,
    const float* __restrict__ A_log,
    const float* __restrict__ Dp,
    const unsigned short* __restrict__ op_b,    // [9][64][128]
    const float* __restrict__ norm_w,
    const float* __restrict__ norm_f_w,
    const float* __restrict__ fusion_w,
    const int* __restrict__ Aflag)              // [9] uniform-A flags
{
    const int b = blockIdx.x, s = blockIdx.y, tid = threadIdx.x;
    const int wave = tid >> 6, lane = tid & 63;
    const int nl = lane & 15, quad = lane >> 4;

    __shared__ float          xt  [Lq][76];     // residual stream (fp32), stride 76
    __shared__ unsigned short u_lb[Lq][136];    // bf16 u; z in place after scan
    __shared__ unsigned short rs_lb[Lq][132];   // bf16 silu(res)
    __shared__ __align__(16) char un_buf[6560]; // union: xn (A->B) | dbl (D->F)
    unsigned short (*xn_lb)[72] = (unsigned short(*)[72])un_buf;
    float          (*dbl_s)[40] = (float(*)[40])un_buf;

    // ---- residual init from embedding (layer 0) --------------------------
    for (int l = wave; l < Lq; l += 4) {
        int id = ids[b * Lq + l];
        xt[l][lane] = emb[id * Dq + lane];
    }

    for (int layer = 0; layer < NLq; ++layer) {
        const int sl = s * NLq + layer;

        // ---- A: rmsnorm(xt) -> xn bf16 -----------------------------------
        {
            const float nwv = norm_w[(size_t)sl * Dq + lane];
            for (int l = wave; l < Lq; l += 4) {
                float v  = xt[l][lane];
                float ss = v * v;
                #pragma unroll
                for (int off = 32; off; off >>= 1) ss += __shfl_xor(ss, off, 64);
                float scale = __builtin_amdgcn_rsqf(ss * (1.0f / Dq) + 1e-5f);
                xn_lb[l][lane] = f2b_tr(v * scale * nwv);
            }
        }
        __syncthreads();

        // ---- B: [48,64]@[64,256] MFMA -> u (cols<128), silu -> rs --------
        {
            #pragma unroll
            for (int t = 0; t < 12; ++t) {
                const int id = wave * 12 + t;
                const int mt = id >> 4, nt = id & 15;
                int ar = mt * 16 + nl; if (ar > Lq - 1) ar = Lq - 1;   // rows>40: clamp, output discarded
                const unsigned short* Wp = Wb_in + ((size_t)(sl * 256 + nt * 16 + nl)) * 64 + quad * 8;
                frag8 a0 = *(const frag8*)&xn_lb[ar][quad * 8];
                frag8 a1 = *(const frag8*)&xn_lb[ar][32 + quad * 8];
                frag8 b0 = *(const frag8*)&Wp[0];
                frag8 b1 = *(const frag8*)&Wp[32];
                f32x4 c = {0.f, 0.f, 0.f, 0.f};
                c = __builtin_amdgcn_mfma_f32_16x16x32_bf16(a0, b0, c, 0, 0, 0);
                c = __builtin_amdgcn_mfma_f32_16x16x32_bf16(a1, b1, c, 0, 0, 0);
                const int col = nt * 16 + nl;
                const int r0 = mt * 16 + quad * 4;
                if (col < DIq) {
                    #pragma unroll
                    for (int r = 0; r < 4; ++r) {
                        int row = r0 + r;
                        if (row < Lq) u_lb[row][col] = f2b_tr(c[r]);
                    }
                } else {
                    const int d = col - DIq;
                    #pragma unroll
                    for (int r = 0; r < 4; ++r) {
                        int row = r0 + r;
                        if (row < Lq) {
                            float v = c[r];
                            rs_lb[row][d] = f2b_tr(v * fast_rcp(1.f + __expf(-v)));
                        }
                    }
                }
            }
        }
        __syncthreads();

        // ---- C: depthwise causal conv (K=4) + bias + silu, in place ------
        {
            const float* cw = conv_w + (size_t)sl * (DIq * Kq);
            const int d = tid >> 1, half = tid & 1;
            const float c0 = cw[d*4+0], c1 = cw[d*4+1], c2 = cw[d*4+2], c3 = cw[d*4+3];
            const float cbv = conv_b[(size_t)sl * DIq + d];
            float w0 = 0.f, w1 = 0.f, w2 = 0.f;
            if (half) { w0 = b2f(u_lb[18][d]); w1 = b2f(u_lb[19][d]); w2 = b2f(u_lb[20][d]); }
            const int base = half ? 21 : 0;
            const int cnt  = half ? 20 : 21;
            for (int i = 0; i < cnt; ++i) {
                int l = base + i;
                float cur = b2f(u_lb[l][d]);
                float a = fmaf(w0, c0, fmaf(w1, c1, fmaf(w2, c2, fmaf(cur, c3, cbv))));
                u_lb[l][d] = f2b_tr(a * fast_rcp(1.f + __expf(-a)));
                w0 = w1; w1 = w2; w2 = cur;
            }
        }
        __syncthreads();

        // ---- D: dbl = u[48,128] @ xp[128,48] MFMA (keep cols<40) ---------
        {
            for (int t = wave; t < 9; t += 4) {
                const int mt = t / 3, ct = t % 3;
                int ar = mt * 16 + nl; if (ar > Lq - 1) ar = Lq - 1;
                f32x4 c = {0.f, 0.f, 0.f, 0.f};
                #pragma unroll
                for (int kt = 0; kt < 4; ++kt) {
                    frag8 a  = *(const frag8*)&u_lb[ar][kt * 32 + quad * 8];
                    frag8 bb = *(const frag8*)&xp_b[((size_t)(sl * 48 + ct * 16 + nl)) * 128 + kt * 32 + quad * 8];
                    c = __builtin_amdgcn_mfma_f32_16x16x32_bf16(a, bb, c, 0, 0, 0);
                }
                const int col = ct * 16 + nl, r0 = mt * 16 + quad * 4;
                if (col < 40) {
                    #pragma unroll
                    for (int r = 0; r < 4; ++r) {
                        int row = r0 + r;
                        if (row < Lq) dbl_s[row][col] = c[r];
                    }
                }
            }
        }
        __syncthreads();

        // ---- F: selective scan, fp32 state; z -> u_lb in place -----------
        // Paired softplus (dt shared by lane pair via shfl_xor); geometric
        // dA chain when Aflag[sl].
        {
            const int d = tid >> 1, half = tid & 1;
            const float* al = A_log + (size_t)sl * (DIq * Nq) + d * Nq + half * 8;
            float A2[8], h[8];
            #pragma unroll
            for (int n = 0; n < 8; ++n) {
                A2[n] = -__expf(al[n]) * 1.442695041f;   // fold log2(e) into A
                h[n] = 0.f;
            }
            const float dd = A2[1] - A2[0];
            const bool fastA = __builtin_amdgcn_readfirstlane(Aflag[sl]) != 0;
            const float* dw = dt_w + (size_t)sl * (DTRq * DIq);
            const float dw0 = dw[d], dw1 = dw[DIq + d], dw2 = dw[2*DIq + d], dw3 = dw[3*DIq + d];
            const float dbv = dt_b[(size_t)sl * DIq + d];
            const float dpd = Dp[(size_t)sl * DIq + d];

            auto step = [&](int l, float dt_) {
                float u_  = b2f(u_lb[l][d]);
                float4 B0 = *(const float4*)&dbl_s[l][4  + half * 8];
                float4 B1 = *(const float4*)&dbl_s[l][8  + half * 8];
                float4 C0 = *(const float4*)&dbl_s[l][20 + half * 8];
                float4 C1 = *(const float4*)&dbl_s[l][24 + half * 8];
                float dtu = dt_ * u_;
                float a0, a1, a2, a3, a4, a5, a6, a7;      // dA as named scalars
                if (fastA) {
                    a0 = __builtin_amdgcn_exp2f(dt_ * A2[0]);
                    float r = __builtin_amdgcn_exp2f(dt_ * dd);
                    a1 = a0 * r; a2 = a1 * r; a3 = a2 * r; a4 = a3 * r;
                    a5 = a4 * r; a6 = a5 * r; a7 = a6 * r;
                } else {
                    a0 = __builtin_amdgcn_exp2f(dt_ * A2[0]);
                    a1 = __builtin_amdgcn_exp2f(dt_ * A2[1]);
                    a2 = __builtin_amdgcn_exp2f(dt_ * A2[2]);
                    a3 = __builtin_amdgcn_exp2f(dt_ * A2[3]);
                    a4 = __builtin_amdgcn_exp2f(dt_ * A2[4]);
                    a5 = __builtin_amdgcn_exp2f(dt_ * A2[5]);
                    a6 = __builtin_amdgcn_exp2f(dt_ * A2[6]);
                    a7 = __builtin_amdgcn_exp2f(dt_ * A2[7]);
                }
                float y = 0.f;
                h[0] = fmaf(a0, h[0], B0.x * dtu); y = fmaf(h[0], C0.x, y);
                h[1] = fmaf(a1, h[1], B0.y * dtu); y = fmaf(h[1], C0.y, y);
                h[2] = fmaf(a2, h[2], B0.z * dtu); y = fmaf(h[2], C0.z, y);
                h[3] = fmaf(a3, h[3], B0.w * dtu); y = fmaf(h[3], C0.w, y);
                h[4] = fmaf(a4, h[4], B1.x * dtu); y = fmaf(h[4], C1.x, y);
                h[5] = fmaf(a5, h[5], B1.y * dtu); y = fmaf(h[5], C1.y, y);
                h[6] = fmaf(a6, h[6], B1.z * dtu); y = fmaf(h[6], C1.z, y);
                h[7] = fmaf(a7, h[7], B1.w * dtu); y = fmaf(h[7], C1.w, y);
                y += __shfl_xor(y, 1, 64);
                if (!half) {
                    float rsv = b2f(rs_lb[l][d]);
                    u_lb[l][d] = f2b_tr(fmaf(u_, dpd, y) * rsv);
                }
            };

            for (int l0 = 0; l0 < Lq; l0 += 2) {
                int lme = l0 + half; if (lme > Lq - 1) lme = Lq - 1;
                float4 q0 = *(const float4*)&dbl_s[lme][0];
                float x = fmaf(q0.x, dw0, fmaf(q0.y, dw1, fmaf(q0.z, dw2, fmaf(q0.w, dw3, dbv))));
                float dts = fmaxf(x, 0.f) + __logf(1.f + __expf(-fabsf(x)));
                float dto = __shfl_xor(dts, 1, 64);
                step(l0, half ? dto : dts);
                if (l0 + 1 < Lq) step(l0 + 1, half ? dts : dto);
            }
        }
        __syncthreads();

        // ---- G: xt += z[48,128] @ op[128,64] MFMA (LDS accumulate) -------
        {
            const int ntG = wave;
            for (int mt = 0; mt < 3; ++mt) {
                int ar = mt * 16 + nl; if (ar > Lq - 1) ar = Lq - 1;
                f32x4 c = {0.f, 0.f, 0.f, 0.f};
                #pragma unroll
                for (int kt = 0; kt < 4; ++kt) {
                    frag8 a  = *(const frag8*)&u_lb[ar][kt * 32 + quad * 8];
                    frag8 bb = *(const frag8*)&op_b[((size_t)(sl * 64 + ntG * 16 + nl)) * 128 + kt * 32 + quad * 8];
                    c = __builtin_amdgcn_mfma_f32_16x16x32_bf16(a, bb, c, 0, 0, 0);
                }
                const int j = ntG * 16 + nl, r0 = mt * 16 + quad * 4;
                #pragma unroll
                for (int r = 0; r < 4; ++r) {
                    int row = r0 + r;
                    if (row < Lq) xt[row][j] += c[r];
                }
            }
        }
        __syncthreads();
    }

    // ---- Epilogue: fused final rmsnorm + fusion weighting -> Xn bf16 -----
    {
        float fw0 = fusion_w[0], fw1 = fusion_w[1], fw2 = fusion_w[2];
        float mx = fmaxf(fw0, fmaxf(fw1, fw2));
        float e0 = __expf(fw0 - mx), e1 = __expf(fw1 - mx), e2 = __expf(fw2 - mx);
        float sw = (s == 0 ? e0 : (s == 1 ? e1 : e2)) * fast_rcp(e0 + e1 + e2);
        float nf = norm_f_w[lane] * sw;
        unsigned short* xr = Xn + ((size_t)s * Bq + b) * FLATq;
        for (int l = wave; l < Lq; l += 4) {
            float v  = xt[l][lane];
            float ss = v * v;
            #pragma unroll
            for (int off = 32; off; off >>= 1) ss += __shfl_xor(ss, off, 64);
            float scale = __builtin_amdgcn_rsqf(ss * (1.0f / Dq) + 1e-5f);
            xr[l * Dq + lane] = f2b_tr(v * scale * nf);
        }
    }
}

// ---------------------------------------------------------------------------
// head_gemm1: H1 = relu( (Σ_s Xn_s) @ W1 + b1 ). 192 blocks on 256 CUs ->
// single-block latency matters: 3 independent accumulators (c0/c1/c2, summed
// at the end) give 3x MFMA ILP (round-14: confirmed ~4 µs total win).
// ---------------------------------------------------------------------------
__global__ __launch_bounds__(256) void head_gemm1(const unsigned short* __restrict__ Xn,
                                                  const unsigned short* __restrict__ W1b,
                                                  const float* __restrict__ b1,
                                                  float* __restrict__ H1) {
    const int tid = threadIdx.x;
    const int wave = tid >> 6, lane = tid & 63;
    const int nl = lane & 15, quad = lane >> 4;
    const int mt = blockIdx.x, nt = blockIdx.y;

    __shared__ float red[4][16][17];

    const int kbeg = (wave < 2) ? wave * 21 : 42 + (wave - 2) * 20;
    const int kcnt = (wave < 2) ? 21 : 20;
    const size_t SB = (size_t)Bq * FLATq;
    const unsigned short* A0 = Xn  + (size_t)(mt * 16 + nl) * FLATq + quad * 8;
    const unsigned short* Br = W1b + (size_t)(nt * 16 + nl) * FLATq + quad * 8;

    f32x4 c0 = {0.f, 0.f, 0.f, 0.f};
    f32x4 c1 = {0.f, 0.f, 0.f, 0.f};
    f32x4 c2 = {0.f, 0.f, 0.f, 0.f};
    for (int ks = kbeg; ks < kbeg + kcnt; ++ks) {
        const int off = ks * 32;
        frag8 bb = *(const frag8*)(Br + off);
        frag8 a0 = *(const frag8*)(A0 + off);
        frag8 a1 = *(const frag8*)(A0 + SB + off);
        frag8 a2 = *(const frag8*)(A0 + 2 * SB + off);
        c0 = __builtin_amdgcn_mfma_f32_16x16x32_bf16(a0, bb, c0, 0, 0, 0);
        c1 = __builtin_amdgcn_mfma_f32_16x16x32_bf16(a1, bb, c1, 0, 0, 0);
        c2 = __builtin_amdgcn_mfma_f32_16x16x32_bf16(a2, bb, c2, 0, 0, 0);
    }
    #pragma unroll
    for (int r = 0; r < 4; ++r) red[wave][quad * 4 + r][nl] = c0[r] + c1[r] + c2[r];
    __syncthreads();

    const int row = tid >> 4, colv = tid & 15;
    float acc = red[0][row][colv] + red[1][row][colv]
              + red[2][row][colv] + red[3][row][colv];
    const int col = nt * 16 + colv;
    H1[(size_t)(mt * 16 + row) * H1q + col] = fmaxf(acc + b1[col], 0.f);
}

// ---------------------------------------------------------------------------
// head_final: h2 = relu(H1@W2+b2); out = sigmoid(h2@W3+b3). 16 batches/block.
// ---------------------------------------------------------------------------
__global__ __launch_bounds__(256) void head_final(const float* __restrict__ H1,
                                                  const float* __restrict__ W2,
                                                  const float* __restrict__ b2,
                                                  const float* __restrict__ W3,
                                                  const float* __restrict__ b3,
                                                  float* __restrict__ out) {
    const int b0 = blockIdx.x * 16, tid = threadIdx.x;
    __shared__ float H1s[16 * H1q];
    __shared__ float h2s[16][16];
    for (int idx = tid; idx < 16 * H1q; idx += 256)
        H1s[idx] = H1[(size_t)b0 * H1q + idx];
    __syncthreads();
    {
        const int row = tid >> 4, g = tid & 15;
        float acc = b2[g];
        for (int k = 0; k < H1q; ++k)
            acc = fmaf(H1s[row * H1q + k], W2[k * H2q + g], acc);
        h2s[row][g] = fmaxf(acc, 0.f);
    }
    __syncthreads();
    if (tid < 16) {
        float z = b3[0];
        #pragma unroll
        for (int k = 0; k < H2q; ++k) z = fmaf(h2s[tid][k], W3[k], z);
        out[b0 + tid] = fast_rcp(1.f + __expf(-z));
    }
}

// ---------------------------------------------------------------------------
extern "C" void kernel_launch(void* const* d_in, const int* in_sizes, int n_in,
                              void* d_out, int out_size, void* d_ws, size_t ws_size,
                              hipStream_t stream) {
    const int*   ids      = (const int*)  d_in[0];
    const float* emb      = (const float*)d_in[1];
    const float* in_proj  = (const float*)d_in[2];
    const float* conv_w   = (const float*)d_in[3];
    const float* conv_b   = (const float*)d_in[4];
    const float* x_proj   = (const float*)d_in[5];
    const float* dt_w     = (const float*)d_in[6];
    const float* dt_b     = (const float*)d_in[7];
    const float* A_log    = (const float*)d_in[8];
    const float* Dp       = (const float*)d_in[9];
    const float* out_proj = (const float*)d_in[10];
    const float* norm_w   = (const float*)d_in[11];
    const float* norm_f_w = (const float*)d_in[12];
    const float* fusion_w = (const float*)d_in[13];
    const float* W1       = (const float*)d_in[14];
    const float* b1       = (const float*)d_in[15];
    const float* W2       = (const float*)d_in[16];
    const float* b2       = (const float*)d_in[17];
    const float* W3       = (const float*)d_in[18];
    const float* b3       = (const float*)d_in[19];
    float* out = (float*)d_out;

    // workspace (shorts unless noted):
    //   Xn    3*512*2624 = 4,030,464
    //   Wb_in   147,456 | xp_b 55,296 | op_b 73,728 | W1b 1,007,616
    //   H1 (fp32) 512*384 = 196,608 floats
    //   Aflag: aliased onto the first 9 ints of H1 (prep writes, mamba_stack
    //   reads, head_gemm1 overwrites H1 only after mamba_stack completes).
    unsigned short* Xn    = (unsigned short*)d_ws;
    unsigned short* Wb_in = Xn    + (size_t)NSq * Bq * FLATq;
    unsigned short* xp_b  = Wb_in + 9*256*64;
    unsigned short* op_b  = xp_b  + 9*48*128;
    unsigned short* W1b   = op_b  + 9*64*128;
    float*          H1    = (float*)(W1b + (size_t)H1q * FLATq);
    int*            Aflag = (int*)H1;

    hipLaunchKernelGGL(prep_kernel, dim3(246 + 1080 + 1), dim3(256), 0, stream,
                       W1, in_proj, x_proj, out_proj, A_log, W1b, Wb_in, xp_b, op_b, Aflag);

    hipLaunchKernelGGL(mamba_stack, dim3(Bq, NSq), dim3(256), 0, stream,
                       Xn, ids, emb, Wb_in, conv_w, conv_b, xp_b, dt_w, dt_b,
                       A_log, Dp, op_b, norm_w, norm_f_w, fusion_w, Aflag);

    hipLaunchKernelGGL(head_gemm1, dim3(Bq/16, H1q/64), dim3(256), 0, stream,
                       Xn, W1b, b1, H1);

    hipLaunchKernelGGL(head_final, dim3(Bq/16), dim3(256), 0, stream,
                       H1, W2, b2, W3, b3, out);
}